// Round 7
// baseline (364.034 us; speedup 1.0000x reference)
//
#include <hip/hip_runtime.h>
#include <hip/hip_bf16.h>
#include <math.h>

#define NN 40000
#define EE 640000
#define MPAD 40064           // NN rounded up to 128 for MFMA tile staging
#define LDS_STRIDE 136       // bf16 elems per LDS row (128 + 8 pad)

typedef short bf16x8 __attribute__((ext_vector_type(8)));
typedef float f32x16 __attribute__((ext_vector_type(16)));

// ---- bf16 helpers ---------------------------------------------------------
__device__ __forceinline__ unsigned bf16rne(float x) {
  unsigned u = __float_as_uint(x);
  return (u + 0x7fffu + ((u >> 16) & 1u)) >> 16;
}
__device__ __forceinline__ unsigned packbf2(float lo, float hi) {
  return bf16rne(lo) | (bf16rne(hi) << 16);
}
__device__ __forceinline__ float bflo(unsigned u) {
  return __uint_as_float(u << 16);
}
__device__ __forceinline__ float bfhi(unsigned u) {
  return __uint_as_float(u & 0xffff0000u);
}

// ---------------------------------------------------------------------------
// in-degree counts; 1 edge/thread (R6: 4/thread at 625 blocks gave only 20%
// occupancy — dependent atomic chains need more waves in flight, not fewer)
// ---------------------------------------------------------------------------
__global__ __launch_bounds__(256) void edge_pass1(
    const int* __restrict__ dst, int* __restrict__ cnt) {
  int e = blockIdx.x * 256 + threadIdx.x;
  if (e < EE) atomicAdd(&cnt[dst[e]], 1);
}

// ---------------------------------------------------------------------------
// single-block chunked scan, fully coalesced (see R3 post-mortem).
// ---------------------------------------------------------------------------
__global__ __launch_bounds__(1024) void scan_kernel(
    const int4* __restrict__ cnt4, int* __restrict__ row_off,
    int* __restrict__ cursor, float* __restrict__ dis) {
  __shared__ int wsum[16];
  __shared__ int btot;
  int t = threadIdx.x;
  int lane = t & 63, w = t >> 6;
  int running = 0;
  for (int c = 0; c < 10; c++) {
    int idx4 = c * 1024 + t;
    bool ok = idx4 * 4 < NN;
    int4 v = ok ? cnt4[idx4] : int4{0, 0, 0, 0};
    int ts = v.x + v.y + v.z + v.w;
    int incl = ts;
#pragma unroll
    for (int off = 1; off < 64; off <<= 1) {
      int u = __shfl_up(incl, off, 64);
      if (lane >= off) incl += u;
    }
    if (lane == 63) wsum[w] = incl;
    __syncthreads();
    if (t < 16) {
      int x = wsum[t];
#pragma unroll
      for (int off = 1; off < 16; off <<= 1) {
        int u = __shfl_up(x, off, 64);
        if (t >= off) x += u;
      }
      wsum[t] = x;
      if (t == 15) btot = x;
    }
    __syncthreads();
    int base = running + (w ? wsum[w - 1] : 0) + (incl - ts);
    if (ok) {
      int4 r;
      r.x = base;
      r.y = base + v.x;
      r.z = r.y + v.y;
      r.w = r.z + v.z;
      ((int4*)row_off)[idx4] = r;
      ((int4*)cursor)[idx4] = r;
      float4 d;
      d.x = rsqrtf((float)(v.x + 1));
      d.y = rsqrtf((float)(v.y + 1));
      d.z = rsqrtf((float)(v.z + 1));
      d.w = rsqrtf((float)(v.w + 1));
      ((float4*)dis)[idx4] = d;
    }
    running += btot;
    __syncthreads();
  }
  if (t == 0) row_off[NN] = running;
}

// ---------------------------------------------------------------------------
// CSR fill; 1 edge/thread for TLP (see edge_pass1 note)
// ---------------------------------------------------------------------------
__global__ __launch_bounds__(256) void fill_kernel(
    const int* __restrict__ src, const int* __restrict__ dst,
    int* __restrict__ cursor, int* __restrict__ csr_src) {
  int e = blockIdx.x * 256 + threadIdx.x;
  if (e < EE) {
    int p = atomicAdd(&cursor[dst[e]], 1);
    csr_src[p] = src[e];
  }
}

// ---------------------------------------------------------------------------
// reg_loss via CSR row scan, masked aligned int4 loads
// ---------------------------------------------------------------------------
__global__ __launch_bounds__(256) void reg_csr(
    const int* __restrict__ src, const int* __restrict__ dst,
    const int* __restrict__ row_off, const int* __restrict__ csr_src,
    float* __restrict__ out_scalar, int E) {
  int e = blockIdx.x * 256 + threadIdx.x;
  int c = 0;
  if (e < E) {
    int i = src[e], j = dst[e];
    int b = row_off[i], en = row_off[i + 1];
    int q0 = b >> 2, q1 = (en + 3) >> 2;
    for (int q = q0; q < q1; q++) {
      int4 v = ((const int4*)csr_src)[q];
      int k = q * 4;
      c += (v.x == j && k + 0 >= b && k + 0 < en);
      c += (v.y == j && k + 1 >= b && k + 1 < en);
      c += (v.z == j && k + 2 >= b && k + 2 < en);
      c += (v.w == j && k + 3 >= b && k + 3 < en);
    }
  }
  float v = (float)c;
  for (int off = 32; off; off >>= 1) v += __shfl_down(v, off, 64);
  __shared__ float ws[4];
  int lane = threadIdx.x & 63, w = threadIdx.x >> 6;
  if (lane == 0) ws[w] = v;
  __syncthreads();
  if (threadIdx.x == 0) atomicAdd(out_scalar, ws[0] + ws[1] + ws[2] + ws[3]);
}

// ---------------------------------------------------------------------------
// fp32 X -> bf16 table scaled by dis[row]: T[s] = dis[s]*X[s]
// ---------------------------------------------------------------------------
__global__ __launch_bounds__(256) void cvt_bf16(const float4* __restrict__ in,
                                                const float* __restrict__ dis,
                                                uint2* __restrict__ outp,
                                                int n8) {
  int i = blockIdx.x * 256 + threadIdx.x;
  if (i >= n8) return;
  float di = dis[i >> 4];
  float4 a = in[i * 2], b = in[i * 2 + 1];
  uint2 o;
  o.x = packbf2(di * a.x, di * a.y);
  o.y = packbf2(di * a.z, di * a.w);
  outp[i * 2] = o;
  uint2 p;
  p.x = packbf2(di * b.x, di * b.y);
  p.y = packbf2(di * b.z, di * b.w);
  outp[i * 2 + 1] = p;
}

// ---------------------------------------------------------------------------
// W[k][n] fp32 -> Wt[n][k] bf16 (once per layer; feeds MFMA B-operand)
// ---------------------------------------------------------------------------
__global__ __launch_bounds__(128) void cvt_wt(const float* __restrict__ W1,
                                              const float* __restrict__ W2,
                                              unsigned short* __restrict__ Wt1,
                                              unsigned short* __restrict__ Wt2) {
  int n = blockIdx.x & 127;
  const float* W = (blockIdx.x < 128) ? W1 : W2;
  unsigned short* Wt = (blockIdx.x < 128) ? Wt1 : Wt2;
  int k = threadIdx.x;
  Wt[n * 128 + k] = (unsigned short)bf16rne(W[k * 128 + n]);
}

// ---------------------------------------------------------------------------
// 128-wide aggregation, 4-edge-slot layout (R6 restructure):
// lane = (slot s = lane>>4, chunk c = lane&15). Each VMEM instruction
// gathers 4 edge rows x 16B = 1KB (16B/lane sweet spot, 4x fewer instrs,
// 4-deep MLP). Masked-FMA tail; shfl_xor(16,32) slot reduction; slot 0
// writes the bf16-packed dis-scaled row (MFMA A-operand table).
// ---------------------------------------------------------------------------
__global__ __launch_bounds__(256) void agg128b(
    const unsigned* __restrict__ Hb, const float* __restrict__ dis,
    const int* __restrict__ row_off, const int* __restrict__ csr_src,
    unsigned* __restrict__ outB) {
  int node = __builtin_amdgcn_readfirstlane(blockIdx.x * 4 + (threadIdx.x >> 6));
  int lane = threadIdx.x & 63;
  int s = lane >> 4, c = lane & 15;
  float a[8] = {};
  int beg = row_off[node], end = row_off[node + 1];
  for (int e = beg; e < end; e += 4) {
    int ei = e + s;
    bool on = ei < end;
    int idx = on ? csr_src[ei] : 0;
    float m = on ? 1.f : 0.f;
    uint4 u = *(const uint4*)&Hb[(size_t)idx * 64 + c * 4];
    a[0] += m * bflo(u.x); a[1] += m * bfhi(u.x);
    a[2] += m * bflo(u.y); a[3] += m * bfhi(u.y);
    a[4] += m * bflo(u.z); a[5] += m * bfhi(u.z);
    a[6] += m * bflo(u.w); a[7] += m * bfhi(u.w);
  }
#pragma unroll
  for (int i = 0; i < 8; i++) {
    a[i] += __shfl_xor(a[i], 16, 64);
    a[i] += __shfl_xor(a[i], 32, 64);
  }
  uint4 v = *(const uint4*)&Hb[(size_t)node * 64 + c * 4];
  float di = dis[node];
  uint4 o;
  o.x = packbf2(di * (a[0] + bflo(v.x)), di * (a[1] + bfhi(v.x)));
  o.y = packbf2(di * (a[2] + bflo(v.y)), di * (a[3] + bfhi(v.y)));
  o.z = packbf2(di * (a[4] + bflo(v.z)), di * (a[5] + bfhi(v.z)));
  o.w = packbf2(di * (a[6] + bflo(v.w)), di * (a[7] + bfhi(v.w)));
  if (s == 0) *(uint4*)&outB[(size_t)node * 64 + c * 4] = o;
}

// ---------------------------------------------------------------------------
// MFMA bf16 GEMM (see R5): 128x128 tile, 32x32x16, 4 waves x 4 n-tiles
// ---------------------------------------------------------------------------
__global__ __launch_bounds__(256) void gemm_mfma(
    const unsigned* __restrict__ Ab, const unsigned* __restrict__ Wt,
    const float* __restrict__ bias, const float* __restrict__ dis,
    float* __restrict__ outF, unsigned short* __restrict__ outB, int outMode) {
  __shared__ unsigned short At[128 * LDS_STRIDE];
  __shared__ unsigned short Bt[128 * LDS_STRIDE];
  int t = threadIdx.x;
  int rowBase = blockIdx.x * 128;
  {
    const uint4* ga = (const uint4*)(Ab + (size_t)rowBase * 64);
    const uint4* gw = (const uint4*)Wt;
#pragma unroll
    for (int i = 0; i < 8; i++) {
      int idx = i * 256 + t;
      int r = idx >> 4, c = idx & 15;
      uint4 va = ga[idx];
      uint4 vw = gw[idx];
      *(uint4*)&At[r * LDS_STRIDE + c * 8] = va;
      *(uint4*)&Bt[r * LDS_STRIDE + c * 8] = vw;
    }
  }
  __syncthreads();
  int lane = t & 63, w = t >> 6;
  int m31 = lane & 31;
  int khalf = (lane >> 5) * 8;
  f32x16 acc[4] = {};
#pragma unroll
  for (int ks = 0; ks < 8; ks++) {
    bf16x8 a = *(bf16x8*)&At[(w * 32 + m31) * LDS_STRIDE + ks * 16 + khalf];
#pragma unroll
    for (int nt = 0; nt < 4; nt++) {
      bf16x8 b = *(bf16x8*)&Bt[(nt * 32 + m31) * LDS_STRIDE + ks * 16 + khalf];
      acc[nt] = __builtin_amdgcn_mfma_f32_32x32x16_bf16(a, b, acc[nt], 0, 0, 0);
    }
  }
  int rsel = (lane >> 5) * 4;
#pragma unroll
  for (int nt = 0; nt < 4; nt++) {
    int col = nt * 32 + m31;
    float bv = bias[col];
#pragma unroll
    for (int r = 0; r < 16; r++) {
      int row = rowBase + w * 32 + (r & 3) + 8 * (r >> 2) + rsel;
      if (row < NN) {
        float x = fmaxf(acc[nt][r] + bv, 0.f);
        if (outMode == 0) {
          outF[(size_t)row * 128 + col] = x;
        } else {
          outB[(size_t)row * 128 + col] = (unsigned short)bf16rne(dis[row] * x);
        }
      }
    }
  }
}

// ---------------------------------------------------------------------------
// GEMM 128 -> 40: one wave per row, W3 in LDS; writes dis-scaled G padded to
// 64 floats/row (cols 40..63 zero) so agg40_softmax can gather float4s.
// ---------------------------------------------------------------------------
__global__ __launch_bounds__(256) void gemm40(const float* __restrict__ A,
                                              const float* __restrict__ W3,
                                              const float* __restrict__ dis,
                                              float* __restrict__ G) {
  __shared__ float Ws[128 * 40];
  int t = threadIdx.x;
  for (int i = t; i < 128 * 40; i += 256) Ws[i] = W3[i];
  __syncthreads();
  int node = __builtin_amdgcn_readfirstlane(blockIdx.x * 4 + (t >> 6));
  int lane = t & 63;
  int cl = lane < 40 ? lane : 39;
  const float* arow = A + (size_t)node * 128;
  float acc = 0.f;
#pragma unroll 8
  for (int k = 0; k < 128; k++) acc += arow[k] * Ws[k * 40 + cl];
  G[(size_t)node * 64 + lane] = (lane < 40) ? dis[node] * acc : 0.f;
}

// ---------------------------------------------------------------------------
// fused 40-wide aggregation + bias + log_softmax, 4-edge-slot float4 layout
// (G rows padded to 64). Slot-reduce via shfl_xor(16,32); softmax reduce
// over the 16-lane chunk group via shfl_xor(1,2,4,8).
// ---------------------------------------------------------------------------
__global__ __launch_bounds__(256) void agg40_softmax(
    const float* __restrict__ G, const float* __restrict__ dis,
    const int* __restrict__ row_off, const int* __restrict__ csr_src,
    const float* __restrict__ b3, float* __restrict__ outp) {
  int node = __builtin_amdgcn_readfirstlane(blockIdx.x * 4 + (threadIdx.x >> 6));
  int lane = threadIdx.x & 63;
  int s = lane >> 4, c = lane & 15;
  float a[4] = {};
  int beg = row_off[node], end = row_off[node + 1];
  for (int e = beg; e < end; e += 4) {
    int ei = e + s;
    bool on = ei < end;
    int idx = on ? csr_src[ei] : 0;
    float m = on ? 1.f : 0.f;
    float4 g = *(const float4*)&G[(size_t)idx * 64 + c * 4];
    a[0] += m * g.x;
    a[1] += m * g.y;
    a[2] += m * g.z;
    a[3] += m * g.w;
  }
#pragma unroll
  for (int i = 0; i < 4; i++) {
    a[i] += __shfl_xor(a[i], 16, 64);
    a[i] += __shfl_xor(a[i], 32, 64);
  }
  float4 gs = *(const float4*)&G[(size_t)node * 64 + c * 4];
  float di = dis[node];
  bool valid = c < 10;  // cols 4c..4c+3 < 40
  float4 bv = valid ? *(const float4*)&b3[c * 4] : float4{0, 0, 0, 0};
  float o0 = di * (a[0] + gs.x) + bv.x;
  float o1 = di * (a[1] + gs.y) + bv.y;
  float o2 = di * (a[2] + gs.z) + bv.z;
  float o3 = di * (a[3] + gs.w) + bv.w;
  float mx = valid ? fmaxf(fmaxf(o0, o1), fmaxf(o2, o3)) : -1e30f;
#pragma unroll
  for (int off = 1; off < 16; off <<= 1) mx = fmaxf(mx, __shfl_xor(mx, off, 64));
  float ex = valid ? (expf(o0 - mx) + expf(o1 - mx) + expf(o2 - mx) +
                      expf(o3 - mx))
                   : 0.f;
#pragma unroll
  for (int off = 1; off < 16; off <<= 1) ex += __shfl_xor(ex, off, 64);
  float lse = mx + logf(ex);
  if (s == 0 && valid) {
    float4 r = {o0 - lse, o1 - lse, o2 - lse, o3 - lse};
    *(float4*)&outp[(size_t)node * 40 + c * 4] = r;
  }
}

// ---------------------------------------------------------------------------
extern "C" void kernel_launch(void* const* d_in, const int* in_sizes, int n_in,
                              void* d_out, int out_size, void* d_ws,
                              size_t ws_size, hipStream_t stream) {
  const float* X = (const float*)d_in[0];
  const int* ei = (const int*)d_in[1];
  const float* W1 = (const float*)d_in[2];
  const float* b1 = (const float*)d_in[3];
  const float* W2 = (const float*)d_in[4];
  const float* b2 = (const float*)d_in[5];
  const float* W3 = (const float*)d_in[6];
  const float* b3 = (const float*)d_in[7];
  float* out = (float*)d_out;

  const int E = EE;
  const int* src = ei;
  const int* dst = ei + E;

  char* w = (char*)d_ws;
  auto carve = [&](size_t bytes) {
    char* p = w;
    w += (bytes + 255) & ~(size_t)255;
    return p;
  };
  int* cnt = (int*)carve(NN * 4);
  float* dis = (float*)carve(NN * 4);
  int* row_off = (int*)carve((NN + 1) * 4);
  int* cursor = (int*)carve(NN * 4);
  int* csr_src = (int*)carve((size_t)EE * 4);
  unsigned short* Wt1 = (unsigned short*)carve(128 * 128 * 2);
  unsigned short* Wt2 = (unsigned short*)carve(128 * 128 * 2);
  unsigned* Ab = (unsigned*)carve((size_t)MPAD * 128 * 2);  // 10.26 MB
  char* blk = carve((size_t)NN * 128 * 4);                  // 20.5 MB shared
  unsigned* Xb = (unsigned*)blk;                            // bf16 T(X)
  unsigned* H1b = (unsigned*)(blk + (size_t)NN * 128 * 2);  // bf16 T(h1)
  float* h2 = (float*)blk;  // layer-2 fp32 out, alias (Xb,H1b dead by then)
  float* G3 = (float*)Ab;   // layer-3 pre-agg [NN][64], alias (Ab dead)

  hipMemsetAsync(cnt, 0, NN * 4, stream);
  hipMemsetAsync((char*)d_out + (size_t)NN * 40 * 4, 0, 4, stream);

  const int EB = (EE + 255) / 256;  // 2500
  const int WB = NN / 4;            // 10000
  const int GB = MPAD / 128;        // 313

  edge_pass1<<<EB, 256, 0, stream>>>(dst, cnt);
  scan_kernel<<<1, 1024, 0, stream>>>((const int4*)cnt, row_off, cursor, dis);
  fill_kernel<<<EB, 256, 0, stream>>>(src, dst, cursor, csr_src);
  reg_csr<<<EB, 256, 0, stream>>>(src, dst, row_off, csr_src,
                                  out + (size_t)NN * 40, E);

  cvt_wt<<<256, 128, 0, stream>>>(W1, W2, Wt1, Wt2);
  cvt_bf16<<<(NN * 128 / 8 + 255) / 256, 256, 0, stream>>>(
      (const float4*)X, dis, (uint2*)Xb, NN * 128 / 8);
  // layer 1: agg(T(X)) -> Ab bf16 ; MFMA gemm+relu -> T(h1) bf16
  agg128b<<<WB, 256, 0, stream>>>(Xb, dis, row_off, csr_src, Ab);
  gemm_mfma<<<GB, 256, 0, stream>>>(Ab, (const unsigned*)Wt1, b1, dis, nullptr,
                                    (unsigned short*)H1b, 1);
  // layer 2: agg(T(h1)) -> Ab bf16 ; MFMA gemm+relu -> h2 fp32
  agg128b<<<WB, 256, 0, stream>>>(H1b, dis, row_off, csr_src, Ab);
  gemm_mfma<<<GB, 256, 0, stream>>>(Ab, (const unsigned*)Wt2, b2, dis, h2,
                                    nullptr, 0);
  // layer 3: gemm40(h2)*dis -> G3 (64-padded) ; fused agg+softmax -> out
  gemm40<<<WB, 256, 0, stream>>>(h2, W3, dis, G3);
  agg40_softmax<<<WB, 256, 0, stream>>>(G3, dis, row_off, csr_src, b3, out);
}

// Round 8
// 353.705 us; speedup vs baseline: 1.0292x; 1.0292x over previous
//
#include <hip/hip_runtime.h>
#include <hip/hip_bf16.h>
#include <math.h>

#define NN 40000
#define EE 640000
#define MPAD 40064           // NN rounded up to 128 for MFMA tile staging
#define LDS_STRIDE 136       // bf16 elems per LDS row (128 + 8 pad)

typedef short bf16x8 __attribute__((ext_vector_type(8)));
typedef float f32x16 __attribute__((ext_vector_type(16)));

// ---- bf16 helpers ---------------------------------------------------------
__device__ __forceinline__ unsigned bf16rne(float x) {
  unsigned u = __float_as_uint(x);
  return (u + 0x7fffu + ((u >> 16) & 1u)) >> 16;
}
__device__ __forceinline__ unsigned packbf2(float lo, float hi) {
  return bf16rne(lo) | (bf16rne(hi) << 16);
}
__device__ __forceinline__ float bflo(unsigned u) {
  return __uint_as_float(u << 16);
}
__device__ __forceinline__ float bfhi(unsigned u) {
  return __uint_as_float(u & 0xffff0000u);
}

// ---------------------------------------------------------------------------
// in-degree counts; 4 edges/thread int4 (R6-measured config; R7's 1/thread
// was neutral-to-worse)
// ---------------------------------------------------------------------------
__global__ __launch_bounds__(256) void edge_pass1(
    const int4* __restrict__ dst4, int* __restrict__ cnt) {
  int e = blockIdx.x * 256 + threadIdx.x;
  if (e >= EE / 4) return;
  int4 d = dst4[e];
  atomicAdd(&cnt[d.x], 1);
  atomicAdd(&cnt[d.y], 1);
  atomicAdd(&cnt[d.z], 1);
  atomicAdd(&cnt[d.w], 1);
}

// ---------------------------------------------------------------------------
// single-block chunked scan, fully coalesced (see R3 post-mortem).
// ---------------------------------------------------------------------------
__global__ __launch_bounds__(1024) void scan_kernel(
    const int4* __restrict__ cnt4, int* __restrict__ row_off,
    int* __restrict__ cursor, float* __restrict__ dis) {
  __shared__ int wsum[16];
  __shared__ int btot;
  int t = threadIdx.x;
  int lane = t & 63, w = t >> 6;
  int running = 0;
  for (int c = 0; c < 10; c++) {
    int idx4 = c * 1024 + t;
    bool ok = idx4 * 4 < NN;
    int4 v = ok ? cnt4[idx4] : int4{0, 0, 0, 0};
    int ts = v.x + v.y + v.z + v.w;
    int incl = ts;
#pragma unroll
    for (int off = 1; off < 64; off <<= 1) {
      int u = __shfl_up(incl, off, 64);
      if (lane >= off) incl += u;
    }
    if (lane == 63) wsum[w] = incl;
    __syncthreads();
    if (t < 16) {
      int x = wsum[t];
#pragma unroll
      for (int off = 1; off < 16; off <<= 1) {
        int u = __shfl_up(x, off, 64);
        if (t >= off) x += u;
      }
      wsum[t] = x;
      if (t == 15) btot = x;
    }
    __syncthreads();
    int base = running + (w ? wsum[w - 1] : 0) + (incl - ts);
    if (ok) {
      int4 r;
      r.x = base;
      r.y = base + v.x;
      r.z = r.y + v.y;
      r.w = r.z + v.z;
      ((int4*)row_off)[idx4] = r;
      ((int4*)cursor)[idx4] = r;
      float4 d;
      d.x = rsqrtf((float)(v.x + 1));
      d.y = rsqrtf((float)(v.y + 1));
      d.z = rsqrtf((float)(v.z + 1));
      d.w = rsqrtf((float)(v.w + 1));
      ((float4*)dis)[idx4] = d;
    }
    running += btot;
    __syncthreads();
  }
  if (t == 0) row_off[NN] = running;
}

// ---------------------------------------------------------------------------
// CSR fill; 4 edges/thread int4 (R6-measured config)
// ---------------------------------------------------------------------------
__global__ __launch_bounds__(256) void fill_kernel(
    const int4* __restrict__ src4, const int4* __restrict__ dst4,
    int* __restrict__ cursor, int* __restrict__ csr_src) {
  int e = blockIdx.x * 256 + threadIdx.x;
  if (e >= EE / 4) return;
  int4 s = src4[e];
  int4 d = dst4[e];
  int i0 = atomicAdd(&cursor[d.x], 1);
  int i1 = atomicAdd(&cursor[d.y], 1);
  int i2 = atomicAdd(&cursor[d.z], 1);
  int i3 = atomicAdd(&cursor[d.w], 1);
  csr_src[i0] = s.x;
  csr_src[i1] = s.y;
  csr_src[i2] = s.z;
  csr_src[i3] = s.w;
}

// ---------------------------------------------------------------------------
// reg_loss via CSR row scan, masked aligned int4 loads
// ---------------------------------------------------------------------------
__global__ __launch_bounds__(256) void reg_csr(
    const int* __restrict__ src, const int* __restrict__ dst,
    const int* __restrict__ row_off, const int* __restrict__ csr_src,
    float* __restrict__ out_scalar, int E) {
  int e = blockIdx.x * 256 + threadIdx.x;
  int c = 0;
  if (e < E) {
    int i = src[e], j = dst[e];
    int b = row_off[i], en = row_off[i + 1];
    int q0 = b >> 2, q1 = (en + 3) >> 2;
    for (int q = q0; q < q1; q++) {
      int4 v = ((const int4*)csr_src)[q];
      int k = q * 4;
      c += (v.x == j && k + 0 >= b && k + 0 < en);
      c += (v.y == j && k + 1 >= b && k + 1 < en);
      c += (v.z == j && k + 2 >= b && k + 2 < en);
      c += (v.w == j && k + 3 >= b && k + 3 < en);
    }
  }
  float v = (float)c;
  for (int off = 32; off; off >>= 1) v += __shfl_down(v, off, 64);
  __shared__ float ws[4];
  int lane = threadIdx.x & 63, w = threadIdx.x >> 6;
  if (lane == 0) ws[w] = v;
  __syncthreads();
  if (threadIdx.x == 0) atomicAdd(out_scalar, ws[0] + ws[1] + ws[2] + ws[3]);
}

// ---------------------------------------------------------------------------
// fp32 X -> bf16 table scaled by dis[row]: T[s] = dis[s]*X[s]
// ---------------------------------------------------------------------------
__global__ __launch_bounds__(256) void cvt_bf16(const float4* __restrict__ in,
                                                const float* __restrict__ dis,
                                                uint2* __restrict__ outp,
                                                int n8) {
  int i = blockIdx.x * 256 + threadIdx.x;
  if (i >= n8) return;
  float di = dis[i >> 4];
  float4 a = in[i * 2], b = in[i * 2 + 1];
  uint2 o;
  o.x = packbf2(di * a.x, di * a.y);
  o.y = packbf2(di * a.z, di * a.w);
  outp[i * 2] = o;
  uint2 p;
  p.x = packbf2(di * b.x, di * b.y);
  p.y = packbf2(di * b.z, di * b.w);
  outp[i * 2 + 1] = p;
}

// ---------------------------------------------------------------------------
// W[k][n] fp32 -> Wt[n][k] bf16 (once per layer; feeds MFMA B-operand)
// ---------------------------------------------------------------------------
__global__ __launch_bounds__(128) void cvt_wt(const float* __restrict__ W1,
                                              const float* __restrict__ W2,
                                              unsigned short* __restrict__ Wt1,
                                              unsigned short* __restrict__ Wt2) {
  int n = blockIdx.x & 127;
  const float* W = (blockIdx.x < 128) ? W1 : W2;
  unsigned short* Wt = (blockIdx.x < 128) ? Wt1 : Wt2;
  int k = threadIdx.x;
  Wt[n * 128 + k] = (unsigned short)bf16rne(W[k * 128 + n]);
}

// ---------------------------------------------------------------------------
// 128-wide aggregation, 4-edge-slot layout + x2 MLP unroll (R7 post-mortem:
// single-load slot loop exposed full gather latency; two independent
// accumulator banks keep 2x1KB gathers in flight).
// lane = (slot s=lane>>4, chunk c=lane&15); 16B/lane per gather.
// ---------------------------------------------------------------------------
__global__ __launch_bounds__(256) void agg128b(
    const unsigned* __restrict__ Hb, const float* __restrict__ dis,
    const int* __restrict__ row_off, const int* __restrict__ csr_src,
    unsigned* __restrict__ outB) {
  int node = __builtin_amdgcn_readfirstlane(blockIdx.x * 4 + (threadIdx.x >> 6));
  int lane = threadIdx.x & 63;
  int s = lane >> 4, c = lane & 15;
  float a[8] = {};
  float b[8] = {};
  int beg = row_off[node], end = row_off[node + 1];
  int e = beg;
  for (; e + 8 <= end; e += 8) {
    int i0 = csr_src[e + s];
    int i1 = csr_src[e + 4 + s];
    uint4 u0 = *(const uint4*)&Hb[(size_t)i0 * 64 + c * 4];
    uint4 u1 = *(const uint4*)&Hb[(size_t)i1 * 64 + c * 4];
    a[0] += bflo(u0.x); a[1] += bfhi(u0.x);
    a[2] += bflo(u0.y); a[3] += bfhi(u0.y);
    a[4] += bflo(u0.z); a[5] += bfhi(u0.z);
    a[6] += bflo(u0.w); a[7] += bfhi(u0.w);
    b[0] += bflo(u1.x); b[1] += bfhi(u1.x);
    b[2] += bflo(u1.y); b[3] += bfhi(u1.y);
    b[4] += bflo(u1.z); b[5] += bfhi(u1.z);
    b[6] += bflo(u1.w); b[7] += bfhi(u1.w);
  }
  for (; e < end; e += 4) {
    int ei = e + s;
    bool on = ei < end;
    int idx = on ? csr_src[ei] : 0;
    float m = on ? 1.f : 0.f;
    uint4 u = *(const uint4*)&Hb[(size_t)idx * 64 + c * 4];
    a[0] += m * bflo(u.x); a[1] += m * bfhi(u.x);
    a[2] += m * bflo(u.y); a[3] += m * bfhi(u.y);
    a[4] += m * bflo(u.z); a[5] += m * bfhi(u.z);
    a[6] += m * bflo(u.w); a[7] += m * bfhi(u.w);
  }
#pragma unroll
  for (int i = 0; i < 8; i++) {
    a[i] += b[i];
    a[i] += __shfl_xor(a[i], 16, 64);
    a[i] += __shfl_xor(a[i], 32, 64);
  }
  uint4 v = *(const uint4*)&Hb[(size_t)node * 64 + c * 4];
  float di = dis[node];
  uint4 o;
  o.x = packbf2(di * (a[0] + bflo(v.x)), di * (a[1] + bfhi(v.x)));
  o.y = packbf2(di * (a[2] + bflo(v.y)), di * (a[3] + bfhi(v.y)));
  o.z = packbf2(di * (a[4] + bflo(v.z)), di * (a[5] + bfhi(v.z)));
  o.w = packbf2(di * (a[6] + bflo(v.w)), di * (a[7] + bfhi(v.w)));
  if (s == 0) *(uint4*)&outB[(size_t)node * 64 + c * 4] = o;
}

// ---------------------------------------------------------------------------
// MFMA bf16 GEMM (see R5): 128x128 tile, 32x32x16, 4 waves x 4 n-tiles
// ---------------------------------------------------------------------------
__global__ __launch_bounds__(256) void gemm_mfma(
    const unsigned* __restrict__ Ab, const unsigned* __restrict__ Wt,
    const float* __restrict__ bias, const float* __restrict__ dis,
    float* __restrict__ outF, unsigned short* __restrict__ outB, int outMode) {
  __shared__ unsigned short At[128 * LDS_STRIDE];
  __shared__ unsigned short Bt[128 * LDS_STRIDE];
  int t = threadIdx.x;
  int rowBase = blockIdx.x * 128;
  {
    const uint4* ga = (const uint4*)(Ab + (size_t)rowBase * 64);
    const uint4* gw = (const uint4*)Wt;
#pragma unroll
    for (int i = 0; i < 8; i++) {
      int idx = i * 256 + t;
      int r = idx >> 4, c = idx & 15;
      uint4 va = ga[idx];
      uint4 vw = gw[idx];
      *(uint4*)&At[r * LDS_STRIDE + c * 8] = va;
      *(uint4*)&Bt[r * LDS_STRIDE + c * 8] = vw;
    }
  }
  __syncthreads();
  int lane = t & 63, w = t >> 6;
  int m31 = lane & 31;
  int khalf = (lane >> 5) * 8;
  f32x16 acc[4] = {};
#pragma unroll
  for (int ks = 0; ks < 8; ks++) {
    bf16x8 a = *(bf16x8*)&At[(w * 32 + m31) * LDS_STRIDE + ks * 16 + khalf];
#pragma unroll
    for (int nt = 0; nt < 4; nt++) {
      bf16x8 b = *(bf16x8*)&Bt[(nt * 32 + m31) * LDS_STRIDE + ks * 16 + khalf];
      acc[nt] = __builtin_amdgcn_mfma_f32_32x32x16_bf16(a, b, acc[nt], 0, 0, 0);
    }
  }
  int rsel = (lane >> 5) * 4;
#pragma unroll
  for (int nt = 0; nt < 4; nt++) {
    int col = nt * 32 + m31;
    float bv = bias[col];
#pragma unroll
    for (int r = 0; r < 16; r++) {
      int row = rowBase + w * 32 + (r & 3) + 8 * (r >> 2) + rsel;
      if (row < NN) {
        float x = fmaxf(acc[nt][r] + bv, 0.f);
        if (outMode == 0) {
          outF[(size_t)row * 128 + col] = x;
        } else {
          outB[(size_t)row * 128 + col] = (unsigned short)bf16rne(dis[row] * x);
        }
      }
    }
  }
}

// ---------------------------------------------------------------------------
// GEMM 128 -> 40: one wave per row, W3 in LDS; writes dis-scaled G padded to
// 64 floats/row (cols 40..63 zero) so agg40_softmax can gather float4s.
// ---------------------------------------------------------------------------
__global__ __launch_bounds__(256) void gemm40(const float* __restrict__ A,
                                              const float* __restrict__ W3,
                                              const float* __restrict__ dis,
                                              float* __restrict__ G) {
  __shared__ float Ws[128 * 40];
  int t = threadIdx.x;
  for (int i = t; i < 128 * 40; i += 256) Ws[i] = W3[i];
  __syncthreads();
  int node = __builtin_amdgcn_readfirstlane(blockIdx.x * 4 + (t >> 6));
  int lane = t & 63;
  int cl = lane < 40 ? lane : 39;
  const float* arow = A + (size_t)node * 128;
  float acc = 0.f;
#pragma unroll 8
  for (int k = 0; k < 128; k++) acc += arow[k] * Ws[k * 40 + cl];
  G[(size_t)node * 64 + lane] = (lane < 40) ? dis[node] * acc : 0.f;
}

// ---------------------------------------------------------------------------
// fused 40-wide aggregation + bias + log_softmax, 4-edge-slot float4 layout
// with x2 MLP unroll (G rows padded to 64 floats).
// ---------------------------------------------------------------------------
__global__ __launch_bounds__(256) void agg40_softmax(
    const float* __restrict__ G, const float* __restrict__ dis,
    const int* __restrict__ row_off, const int* __restrict__ csr_src,
    const float* __restrict__ b3, float* __restrict__ outp) {
  int node = __builtin_amdgcn_readfirstlane(blockIdx.x * 4 + (threadIdx.x >> 6));
  int lane = threadIdx.x & 63;
  int s = lane >> 4, c = lane & 15;
  float a[4] = {};
  float b[4] = {};
  int beg = row_off[node], end = row_off[node + 1];
  int e = beg;
  for (; e + 8 <= end; e += 8) {
    int i0 = csr_src[e + s];
    int i1 = csr_src[e + 4 + s];
    float4 g0 = *(const float4*)&G[(size_t)i0 * 64 + c * 4];
    float4 g1 = *(const float4*)&G[(size_t)i1 * 64 + c * 4];
    a[0] += g0.x; a[1] += g0.y; a[2] += g0.z; a[3] += g0.w;
    b[0] += g1.x; b[1] += g1.y; b[2] += g1.z; b[3] += g1.w;
  }
  for (; e < end; e += 4) {
    int ei = e + s;
    bool on = ei < end;
    int idx = on ? csr_src[ei] : 0;
    float m = on ? 1.f : 0.f;
    float4 g = *(const float4*)&G[(size_t)idx * 64 + c * 4];
    a[0] += m * g.x;
    a[1] += m * g.y;
    a[2] += m * g.z;
    a[3] += m * g.w;
  }
#pragma unroll
  for (int i = 0; i < 4; i++) {
    a[i] += b[i];
    a[i] += __shfl_xor(a[i], 16, 64);
    a[i] += __shfl_xor(a[i], 32, 64);
  }
  float4 gs = *(const float4*)&G[(size_t)node * 64 + c * 4];
  float di = dis[node];
  bool valid = c < 10;  // cols 4c..4c+3 < 40
  float4 bv = valid ? *(const float4*)&b3[c * 4] : float4{0, 0, 0, 0};
  float o0 = di * (a[0] + gs.x) + bv.x;
  float o1 = di * (a[1] + gs.y) + bv.y;
  float o2 = di * (a[2] + gs.z) + bv.z;
  float o3 = di * (a[3] + gs.w) + bv.w;
  float mx = valid ? fmaxf(fmaxf(o0, o1), fmaxf(o2, o3)) : -1e30f;
#pragma unroll
  for (int off = 1; off < 16; off <<= 1) mx = fmaxf(mx, __shfl_xor(mx, off, 64));
  float ex = valid ? (expf(o0 - mx) + expf(o1 - mx) + expf(o2 - mx) +
                      expf(o3 - mx))
                   : 0.f;
#pragma unroll
  for (int off = 1; off < 16; off <<= 1) ex += __shfl_xor(ex, off, 64);
  float lse = mx + logf(ex);
  if (s == 0 && valid) {
    float4 r = {o0 - lse, o1 - lse, o2 - lse, o3 - lse};
    *(float4*)&outp[(size_t)node * 40 + c * 4] = r;
  }
}

// ---------------------------------------------------------------------------
extern "C" void kernel_launch(void* const* d_in, const int* in_sizes, int n_in,
                              void* d_out, int out_size, void* d_ws,
                              size_t ws_size, hipStream_t stream) {
  const float* X = (const float*)d_in[0];
  const int* ei = (const int*)d_in[1];
  const float* W1 = (const float*)d_in[2];
  const float* b1 = (const float*)d_in[3];
  const float* W2 = (const float*)d_in[4];
  const float* b2 = (const float*)d_in[5];
  const float* W3 = (const float*)d_in[6];
  const float* b3 = (const float*)d_in[7];
  float* out = (float*)d_out;

  const int E = EE;
  const int* src = ei;
  const int* dst = ei + E;

  char* w = (char*)d_ws;
  auto carve = [&](size_t bytes) {
    char* p = w;
    w += (bytes + 255) & ~(size_t)255;
    return p;
  };
  int* cnt = (int*)carve(NN * 4);
  float* dis = (float*)carve(NN * 4);
  int* row_off = (int*)carve((NN + 1) * 4);
  int* cursor = (int*)carve(NN * 4);
  int* csr_src = (int*)carve((size_t)EE * 4);
  unsigned short* Wt1 = (unsigned short*)carve(128 * 128 * 2);
  unsigned short* Wt2 = (unsigned short*)carve(128 * 128 * 2);
  unsigned* Ab = (unsigned*)carve((size_t)MPAD * 128 * 2);  // 10.26 MB
  char* blk = carve((size_t)NN * 128 * 4);                  // 20.5 MB shared
  unsigned* Xb = (unsigned*)blk;                            // bf16 T(X)
  unsigned* H1b = (unsigned*)(blk + (size_t)NN * 128 * 2);  // bf16 T(h1)
  float* h2 = (float*)blk;  // layer-2 fp32 out, alias (Xb,H1b dead by then)
  float* G3 = (float*)Ab;   // layer-3 pre-agg [NN][64], alias (Ab dead)

  hipMemsetAsync(cnt, 0, NN * 4, stream);
  hipMemsetAsync((char*)d_out + (size_t)NN * 40 * 4, 0, 4, stream);

  const int E4B = (EE / 4 + 255) / 256;  // 625
  const int EB = (EE + 255) / 256;       // 2500
  const int WB = NN / 4;                 // 10000
  const int GB = MPAD / 128;             // 313

  edge_pass1<<<E4B, 256, 0, stream>>>((const int4*)dst, cnt);
  scan_kernel<<<1, 1024, 0, stream>>>((const int4*)cnt, row_off, cursor, dis);
  fill_kernel<<<E4B, 256, 0, stream>>>((const int4*)src, (const int4*)dst,
                                       cursor, csr_src);
  reg_csr<<<EB, 256, 0, stream>>>(src, dst, row_off, csr_src,
                                  out + (size_t)NN * 40, E);

  cvt_wt<<<256, 128, 0, stream>>>(W1, W2, Wt1, Wt2);
  cvt_bf16<<<(NN * 128 / 8 + 255) / 256, 256, 0, stream>>>(
      (const float4*)X, dis, (uint2*)Xb, NN * 128 / 8);
  // layer 1: agg(T(X)) -> Ab bf16 ; MFMA gemm+relu -> T(h1) bf16
  agg128b<<<WB, 256, 0, stream>>>(Xb, dis, row_off, csr_src, Ab);
  gemm_mfma<<<GB, 256, 0, stream>>>(Ab, (const unsigned*)Wt1, b1, dis, nullptr,
                                    (unsigned short*)H1b, 1);
  // layer 2: agg(T(h1)) -> Ab bf16 ; MFMA gemm+relu -> h2 fp32
  agg128b<<<WB, 256, 0, stream>>>(H1b, dis, row_off, csr_src, Ab);
  gemm_mfma<<<GB, 256, 0, stream>>>(Ab, (const unsigned*)Wt2, b2, dis, h2,
                                    nullptr, 0);
  // layer 3: gemm40(h2)*dis -> G3 (64-padded) ; fused agg+softmax -> out
  gemm40<<<WB, 256, 0, stream>>>(h2, W3, dis, G3);
  agg40_softmax<<<WB, 256, 0, stream>>>(G3, dis, row_off, csr_src, b3, out);
}

// Round 9
// 313.552 us; speedup vs baseline: 1.1610x; 1.1281x over previous
//
#include <hip/hip_runtime.h>
#include <hip/hip_bf16.h>
#include <math.h>

#define NN 40000
#define EE 640000
#define MPAD 40064           // NN rounded up to 128 for MFMA tile staging
#define LDS_STRIDE 136       // bf16 elems per LDS row (128 + 8 pad)

typedef short bf16x8 __attribute__((ext_vector_type(8)));
typedef float f32x16 __attribute__((ext_vector_type(16)));

// ---- bf16 helpers ---------------------------------------------------------
__device__ __forceinline__ unsigned bf16rne(float x) {
  unsigned u = __float_as_uint(x);
  return (u + 0x7fffu + ((u >> 16) & 1u)) >> 16;
}
__device__ __forceinline__ unsigned packbf2(float lo, float hi) {
  return bf16rne(lo) | (bf16rne(hi) << 16);
}
__device__ __forceinline__ float bflo(unsigned u) {
  return __uint_as_float(u << 16);
}
__device__ __forceinline__ float bfhi(unsigned u) {
  return __uint_as_float(u & 0xffff0000u);
}

// ---------------------------------------------------------------------------
// in-degree counts; 4 edges/thread int4 (R6-measured config)
// ---------------------------------------------------------------------------
__global__ __launch_bounds__(256) void edge_pass1(
    const int4* __restrict__ dst4, int* __restrict__ cnt) {
  int e = blockIdx.x * 256 + threadIdx.x;
  if (e >= EE / 4) return;
  int4 d = dst4[e];
  atomicAdd(&cnt[d.x], 1);
  atomicAdd(&cnt[d.y], 1);
  atomicAdd(&cnt[d.z], 1);
  atomicAdd(&cnt[d.w], 1);
}

// ---------------------------------------------------------------------------
// single-block chunked scan, fully coalesced (see R3 post-mortem).
// ---------------------------------------------------------------------------
__global__ __launch_bounds__(1024) void scan_kernel(
    const int4* __restrict__ cnt4, int* __restrict__ row_off,
    int* __restrict__ cursor, float* __restrict__ dis) {
  __shared__ int wsum[16];
  __shared__ int btot;
  int t = threadIdx.x;
  int lane = t & 63, w = t >> 6;
  int running = 0;
  for (int c = 0; c < 10; c++) {
    int idx4 = c * 1024 + t;
    bool ok = idx4 * 4 < NN;
    int4 v = ok ? cnt4[idx4] : int4{0, 0, 0, 0};
    int ts = v.x + v.y + v.z + v.w;
    int incl = ts;
#pragma unroll
    for (int off = 1; off < 64; off <<= 1) {
      int u = __shfl_up(incl, off, 64);
      if (lane >= off) incl += u;
    }
    if (lane == 63) wsum[w] = incl;
    __syncthreads();
    if (t < 16) {
      int x = wsum[t];
#pragma unroll
      for (int off = 1; off < 16; off <<= 1) {
        int u = __shfl_up(x, off, 64);
        if (t >= off) x += u;
      }
      wsum[t] = x;
      if (t == 15) btot = x;
    }
    __syncthreads();
    int base = running + (w ? wsum[w - 1] : 0) + (incl - ts);
    if (ok) {
      int4 r;
      r.x = base;
      r.y = base + v.x;
      r.z = r.y + v.y;
      r.w = r.z + v.z;
      ((int4*)row_off)[idx4] = r;
      ((int4*)cursor)[idx4] = r;
      float4 d;
      d.x = rsqrtf((float)(v.x + 1));
      d.y = rsqrtf((float)(v.y + 1));
      d.z = rsqrtf((float)(v.z + 1));
      d.w = rsqrtf((float)(v.w + 1));
      ((float4*)dis)[idx4] = d;
    }
    running += btot;
    __syncthreads();
  }
  if (t == 0) row_off[NN] = running;
}

// ---------------------------------------------------------------------------
// CSR fill; 4 edges/thread int4; entries are uint16 (NN<65536) — halves the
// scattered dirty-byte write traffic vs int entries (R8 theory).
// ---------------------------------------------------------------------------
__global__ __launch_bounds__(256) void fill_kernel(
    const int4* __restrict__ src4, const int4* __restrict__ dst4,
    int* __restrict__ cursor, unsigned short* __restrict__ csr) {
  int e = blockIdx.x * 256 + threadIdx.x;
  if (e >= EE / 4) return;
  int4 s = src4[e];
  int4 d = dst4[e];
  int i0 = atomicAdd(&cursor[d.x], 1);
  int i1 = atomicAdd(&cursor[d.y], 1);
  int i2 = atomicAdd(&cursor[d.z], 1);
  int i3 = atomicAdd(&cursor[d.w], 1);
  csr[i0] = (unsigned short)s.x;
  csr[i1] = (unsigned short)s.y;
  csr[i2] = (unsigned short)s.z;
  csr[i3] = (unsigned short)s.w;
}

// ---------------------------------------------------------------------------
// reg_loss via CSR row scan: 8 uint16 entries per aligned 16B load
// ---------------------------------------------------------------------------
__global__ __launch_bounds__(256) void reg_csr(
    const int* __restrict__ src, const int* __restrict__ dst,
    const int* __restrict__ row_off, const unsigned short* __restrict__ csr,
    float* __restrict__ out_scalar, int E) {
  int e = blockIdx.x * 256 + threadIdx.x;
  int c = 0;
  if (e < E) {
    int i = src[e];
    unsigned j = (unsigned)dst[e];
    int b = row_off[i], en = row_off[i + 1];
    int q0 = b >> 3, q1 = (en + 7) >> 3;
    const uint4* base = (const uint4*)csr;
    for (int q = q0; q < q1; q++) {
      uint4 v = base[q];
      int k = q * 8;
      c += ((v.x & 0xffffu) == j && k + 0 >= b && k + 0 < en);
      c += ((v.x >> 16) == j && k + 1 >= b && k + 1 < en);
      c += ((v.y & 0xffffu) == j && k + 2 >= b && k + 2 < en);
      c += ((v.y >> 16) == j && k + 3 >= b && k + 3 < en);
      c += ((v.z & 0xffffu) == j && k + 4 >= b && k + 4 < en);
      c += ((v.z >> 16) == j && k + 5 >= b && k + 5 < en);
      c += ((v.w & 0xffffu) == j && k + 6 >= b && k + 6 < en);
      c += ((v.w >> 16) == j && k + 7 >= b && k + 7 < en);
    }
  }
  float v = (float)c;
  for (int off = 32; off; off >>= 1) v += __shfl_down(v, off, 64);
  __shared__ float ws[4];
  int lane = threadIdx.x & 63, w = threadIdx.x >> 6;
  if (lane == 0) ws[w] = v;
  __syncthreads();
  if (threadIdx.x == 0) atomicAdd(out_scalar, ws[0] + ws[1] + ws[2] + ws[3]);
}

// ---------------------------------------------------------------------------
// merged conversions: blocks [0,2500) X->bf16*dis ; [2500,2564) W1t ;
// [2564,2628) W2t ; [2628,2660) W3t (64x128, rows 40..63 zero)
// ---------------------------------------------------------------------------
__global__ __launch_bounds__(256) void cvt_all(
    const float4* __restrict__ X, const float* __restrict__ dis,
    uint2* __restrict__ Xb, const float* __restrict__ W1,
    const float* __restrict__ W2, const float* __restrict__ W3,
    unsigned short* __restrict__ Wt1, unsigned short* __restrict__ Wt2,
    unsigned short* __restrict__ W3t) {
  int blk = blockIdx.x, t = threadIdx.x;
  if (blk < 2500) {
    int i = blk * 256 + t;  // 8 floats per thread; 2500*256 = 640000 = NN*128/8
    float di = dis[i >> 4];
    float4 a = X[i * 2], b = X[i * 2 + 1];
    uint2 o;
    o.x = packbf2(di * a.x, di * a.y);
    o.y = packbf2(di * a.z, di * a.w);
    Xb[i * 2] = o;
    uint2 p;
    p.x = packbf2(di * b.x, di * b.y);
    p.y = packbf2(di * b.z, di * b.w);
    Xb[i * 2 + 1] = p;
  } else if (blk < 2628) {
    bool is1 = blk < 2564;
    int n = (blk - (is1 ? 2500 : 2564)) * 2 + (t >> 7);
    int k = t & 127;
    const float* W = is1 ? W1 : W2;
    unsigned short* Wt = is1 ? Wt1 : Wt2;
    Wt[n * 128 + k] = (unsigned short)bf16rne(W[k * 128 + n]);
  } else {
    int n = (blk - 2628) * 2 + (t >> 7);
    int k = t & 127;
    float v = (n < 40) ? W3[k * 40 + n] : 0.f;
    W3t[n * 128 + k] = (unsigned short)bf16rne(v);
  }
}

// ---------------------------------------------------------------------------
// 128-wide aggregation, R6-measured form: one wave/node, lane = 2 cols
// (one uint), edge loop unrolled x4 -> 4 independent gathers in flight.
// csr entries are uint16.
// ---------------------------------------------------------------------------
__global__ __launch_bounds__(256) void agg128b(
    const unsigned* __restrict__ Hb, const float* __restrict__ dis,
    const int* __restrict__ row_off, const unsigned short* __restrict__ csr,
    unsigned* __restrict__ outB) {
  int node = __builtin_amdgcn_readfirstlane(blockIdx.x * 4 + (threadIdx.x >> 6));
  int lane = threadIdx.x & 63;
  float di = dis[node];
  unsigned v = Hb[(size_t)node * 64 + lane];
  float a0 = bflo(v), a1 = bfhi(v);
  int beg = row_off[node], end = row_off[node + 1];
  int e = beg;
  for (; e + 4 <= end; e += 4) {
    int s0 = csr[e + 0], s1 = csr[e + 1];
    int s2 = csr[e + 2], s3 = csr[e + 3];
    unsigned u0 = Hb[(size_t)s0 * 64 + lane];
    unsigned u1 = Hb[(size_t)s1 * 64 + lane];
    unsigned u2 = Hb[(size_t)s2 * 64 + lane];
    unsigned u3 = Hb[(size_t)s3 * 64 + lane];
    a0 += bflo(u0); a1 += bfhi(u0);
    a0 += bflo(u1); a1 += bfhi(u1);
    a0 += bflo(u2); a1 += bfhi(u2);
    a0 += bflo(u3); a1 += bfhi(u3);
  }
  for (; e < end; e++) {
    unsigned u = Hb[(size_t)csr[e] * 64 + lane];
    a0 += bflo(u);
    a1 += bfhi(u);
  }
  outB[(size_t)node * 64 + lane] = packbf2(di * a0, di * a1);
}

// ---------------------------------------------------------------------------
// MFMA bf16 GEMM layer-1: 128x128 tile, 32x32x16, 4 waves x 4 n-tiles;
// epilogue writes bf16 gather table scaled by dis[row].
// C/D layout: col=lane&31, row=(reg&3)+8*(reg>>2)+4*(lane>>5)
// ---------------------------------------------------------------------------
__global__ __launch_bounds__(256) void gemm_mfma(
    const unsigned* __restrict__ Ab, const unsigned* __restrict__ Wt,
    const float* __restrict__ bias, const float* __restrict__ dis,
    unsigned short* __restrict__ outB) {
  __shared__ unsigned short At[128 * LDS_STRIDE];
  __shared__ unsigned short Bt[128 * LDS_STRIDE];
  int t = threadIdx.x;
  int rowBase = blockIdx.x * 128;
  {
    const uint4* ga = (const uint4*)(Ab + (size_t)rowBase * 64);
    const uint4* gw = (const uint4*)Wt;
#pragma unroll
    for (int i = 0; i < 8; i++) {
      int idx = i * 256 + t;
      int r = idx >> 4, c = idx & 15;
      uint4 va = ga[idx];
      uint4 vw = gw[idx];
      *(uint4*)&At[r * LDS_STRIDE + c * 8] = va;
      *(uint4*)&Bt[r * LDS_STRIDE + c * 8] = vw;
    }
  }
  __syncthreads();
  int lane = t & 63, w = t >> 6;
  int m31 = lane & 31;
  int khalf = (lane >> 5) * 8;
  f32x16 acc[4] = {};
#pragma unroll
  for (int ks = 0; ks < 8; ks++) {
    bf16x8 a = *(bf16x8*)&At[(w * 32 + m31) * LDS_STRIDE + ks * 16 + khalf];
#pragma unroll
    for (int nt = 0; nt < 4; nt++) {
      bf16x8 b = *(bf16x8*)&Bt[(nt * 32 + m31) * LDS_STRIDE + ks * 16 + khalf];
      acc[nt] = __builtin_amdgcn_mfma_f32_32x32x16_bf16(a, b, acc[nt], 0, 0, 0);
    }
  }
  int rsel = (lane >> 5) * 4;
#pragma unroll
  for (int nt = 0; nt < 4; nt++) {
    int col = nt * 32 + m31;
    float bv = bias[col];
#pragma unroll
    for (int r = 0; r < 16; r++) {
      int row = rowBase + w * 32 + (r & 3) + 8 * (r >> 2) + rsel;
      if (row < NN) {
        float x = fmaxf(acc[nt][r] + bv, 0.f);
        outB[(size_t)row * 128 + col] = (unsigned short)bf16rne(dis[row] * x);
      }
    }
  }
}

// ---------------------------------------------------------------------------
// Fused layer-2 + layer-3 GEMM: phase 1 = relu(A@W2+b2) (h2 tile, regs only);
// write bf16(dis*h2) into At; load W3t (64x128) into Bt; phase 2 MFMA gives
// G3 = (dis*h2)@W3 directly. Kills the h2 global round-trip and gemm40.
// ---------------------------------------------------------------------------
__global__ __launch_bounds__(256) void gemm_mfma2(
    const unsigned* __restrict__ Ab, const unsigned* __restrict__ Wt,
    const float* __restrict__ bias, const float* __restrict__ dis,
    const unsigned short* __restrict__ W3t, float* __restrict__ G3) {
  __shared__ unsigned short At[128 * LDS_STRIDE];
  __shared__ unsigned short Bt[128 * LDS_STRIDE];
  __shared__ float dsh[128];
  int t = threadIdx.x;
  int rowBase = blockIdx.x * 128;
  if (t < 128) {
    int rr = rowBase + t;
    dsh[t] = (rr < NN) ? dis[rr] : 0.f;
  }
  {
    const uint4* ga = (const uint4*)(Ab + (size_t)rowBase * 64);
    const uint4* gw = (const uint4*)Wt;
#pragma unroll
    for (int i = 0; i < 8; i++) {
      int idx = i * 256 + t;
      int r = idx >> 4, c = idx & 15;
      uint4 va = ga[idx];
      uint4 vw = gw[idx];
      *(uint4*)&At[r * LDS_STRIDE + c * 8] = va;
      *(uint4*)&Bt[r * LDS_STRIDE + c * 8] = vw;
    }
  }
  __syncthreads();
  int lane = t & 63, w = t >> 6;
  int m31 = lane & 31;
  int khalf = (lane >> 5) * 8;
  f32x16 acc[4] = {};
#pragma unroll
  for (int ks = 0; ks < 8; ks++) {
    bf16x8 a = *(bf16x8*)&At[(w * 32 + m31) * LDS_STRIDE + ks * 16 + khalf];
#pragma unroll
    for (int nt = 0; nt < 4; nt++) {
      bf16x8 b = *(bf16x8*)&Bt[(nt * 32 + m31) * LDS_STRIDE + ks * 16 + khalf];
      acc[nt] = __builtin_amdgcn_mfma_f32_32x32x16_bf16(a, b, acc[nt], 0, 0, 0);
    }
  }
  __syncthreads();  // everyone done reading At/Bt (phase-1)
  int rsel = (lane >> 5) * 4;
  // write bf16(dis*relu(h2)) into At (own rows only)
#pragma unroll
  for (int nt = 0; nt < 4; nt++) {
    int col = nt * 32 + m31;
    float bv = bias[col];
#pragma unroll
    for (int r = 0; r < 16; r++) {
      int rl = w * 32 + (r & 3) + 8 * (r >> 2) + rsel;
      float x = fmaxf(acc[nt][r] + bv, 0.f);
      At[rl * LDS_STRIDE + col] = (unsigned short)bf16rne(dsh[rl] * x);
    }
  }
  // load W3t (64 rows x 128 k, bf16) into Bt
  {
    const uint4* gw3 = (const uint4*)W3t;
#pragma unroll
    for (int i = 0; i < 4; i++) {
      int idx = i * 256 + t;  // 1024 uint4 = 64*128*2B
      int r = idx >> 4, c = idx & 15;
      *(uint4*)&Bt[r * LDS_STRIDE + c * 8] = gw3[idx];
    }
  }
  __syncthreads();
  f32x16 acc2[2] = {};
#pragma unroll
  for (int ks = 0; ks < 8; ks++) {
    bf16x8 a = *(bf16x8*)&At[(w * 32 + m31) * LDS_STRIDE + ks * 16 + khalf];
#pragma unroll
    for (int nt = 0; nt < 2; nt++) {
      bf16x8 b = *(bf16x8*)&Bt[(nt * 32 + m31) * LDS_STRIDE + ks * 16 + khalf];
      acc2[nt] = __builtin_amdgcn_mfma_f32_32x32x16_bf16(a, b, acc2[nt], 0, 0, 0);
    }
  }
#pragma unroll
  for (int nt = 0; nt < 2; nt++) {
    int col = nt * 32 + m31;
    if (col < 40) {
#pragma unroll
      for (int r = 0; r < 16; r++) {
        int row = rowBase + w * 32 + (r & 3) + 8 * (r >> 2) + rsel;
        if (row < NN) G3[(size_t)row * 40 + col] = acc2[nt][r];
      }
    }
  }
}

// ---------------------------------------------------------------------------
// fused 40-wide aggregation + bias + log_softmax (R6-measured form; G3 is
// pre-scaled by dis[src]); csr entries uint16.
// ---------------------------------------------------------------------------
__global__ __launch_bounds__(256) void agg40_softmax(
    const float* __restrict__ G, const float* __restrict__ dis,
    const int* __restrict__ row_off, const unsigned short* __restrict__ csr,
    const float* __restrict__ b3, float* __restrict__ outp) {
  int node = __builtin_amdgcn_readfirstlane(blockIdx.x * 4 + (threadIdx.x >> 6));
  int lane = threadIdx.x & 63;
  int cl = lane < 40 ? lane : 39;
  float di = dis[node];
  float a = G[(size_t)node * 40 + cl];
  int beg = row_off[node], end = row_off[node + 1];
  int e = beg;
  for (; e + 4 <= end; e += 4) {
    int s0 = csr[e + 0], s1 = csr[e + 1];
    int s2 = csr[e + 2], s3 = csr[e + 3];
    float g0 = G[(size_t)s0 * 40 + cl];
    float g1 = G[(size_t)s1 * 40 + cl];
    float g2 = G[(size_t)s2 * 40 + cl];
    float g3 = G[(size_t)s3 * 40 + cl];
    a += g0 + g1 + g2 + g3;
  }
  for (; e < end; e++) {
    a += G[(size_t)csr[e] * 40 + cl];
  }
  float o = di * a + b3[cl];
  float m = (lane < 40) ? o : -1e30f;
  for (int off = 32; off; off >>= 1) m = fmaxf(m, __shfl_xor(m, off, 64));
  float ex = (lane < 40) ? expf(o - m) : 0.f;
  float ssum = ex;
  for (int off = 32; off; off >>= 1) ssum += __shfl_xor(ssum, off, 64);
  float res = o - m - logf(ssum);
  if (lane < 40) outp[(size_t)node * 40 + lane] = res;
}

// ---------------------------------------------------------------------------
extern "C" void kernel_launch(void* const* d_in, const int* in_sizes, int n_in,
                              void* d_out, int out_size, void* d_ws,
                              size_t ws_size, hipStream_t stream) {
  const float* X = (const float*)d_in[0];
  const int* ei = (const int*)d_in[1];
  const float* W1 = (const float*)d_in[2];
  const float* b1 = (const float*)d_in[3];
  const float* W2 = (const float*)d_in[4];
  const float* b2 = (const float*)d_in[5];
  const float* W3 = (const float*)d_in[6];
  const float* b3 = (const float*)d_in[7];
  float* out = (float*)d_out;

  const int E = EE;
  const int* src = ei;
  const int* dst = ei + E;

  char* w = (char*)d_ws;
  auto carve = [&](size_t bytes) {
    char* p = w;
    w += (bytes + 255) & ~(size_t)255;
    return p;
  };
  int* cnt = (int*)carve(NN * 4);
  float* dis = (float*)carve(NN * 4);
  int* row_off = (int*)carve((NN + 1) * 4);
  int* cursor = (int*)carve(NN * 4);
  unsigned short* csr = (unsigned short*)carve((size_t)EE * 2);
  unsigned short* Wt1 = (unsigned short*)carve(128 * 128 * 2);
  unsigned short* Wt2 = (unsigned short*)carve(128 * 128 * 2);
  unsigned short* W3t = (unsigned short*)carve(64 * 128 * 2);
  unsigned* Ab = (unsigned*)carve((size_t)MPAD * 128 * 2);  // 10.26 MB
  char* blk = carve((size_t)NN * 128 * 4);                  // 20.5 MB shared
  unsigned* Xb = (unsigned*)blk;                            // bf16 T(X)
  unsigned* H1b = (unsigned*)(blk + (size_t)NN * 128 * 2);  // bf16 T(h1)
  float* G3 = (float*)blk;  // layer-3 pre-agg [NN][40]; Xb/H1b dead by then

  hipMemsetAsync(cnt, 0, NN * 4, stream);
  hipMemsetAsync((char*)d_out + (size_t)NN * 40 * 4, 0, 4, stream);

  const int E4B = (EE / 4 + 255) / 256;  // 625
  const int EB = (EE + 255) / 256;       // 2500
  const int WB = NN / 4;                 // 10000
  const int GB = MPAD / 128;             // 313

  edge_pass1<<<E4B, 256, 0, stream>>>((const int4*)dst, cnt);
  scan_kernel<<<1, 1024, 0, stream>>>((const int4*)cnt, row_off, cursor, dis);
  fill_kernel<<<E4B, 256, 0, stream>>>((const int4*)src, (const int4*)dst,
                                       cursor, csr);
  reg_csr<<<EB, 256, 0, stream>>>(src, dst, row_off, csr,
                                  out + (size_t)NN * 40, E);

  cvt_all<<<2660, 256, 0, stream>>>((const float4*)X, dis, (uint2*)Xb, W1, W2,
                                    W3, Wt1, Wt2, W3t);
  // layer 1: agg(T(X)) -> Ab bf16 ; MFMA gemm+relu -> T(h1) bf16
  agg128b<<<WB, 256, 0, stream>>>(Xb, dis, row_off, csr, Ab);
  gemm_mfma<<<GB, 256, 0, stream>>>(Ab, (const unsigned*)Wt1, b1, dis,
                                    (unsigned short*)H1b);
  // layer 2: agg(T(h1)) -> Ab bf16 ; fused MFMA (W2 then W3) -> G3
  agg128b<<<WB, 256, 0, stream>>>(H1b, dis, row_off, csr, Ab);
  gemm_mfma2<<<GB, 256, 0, stream>>>(Ab, (const unsigned*)Wt2, b2, dis, W3t,
                                     G3);
  // layer 3 aggregation + bias + log_softmax -> out
  agg40_softmax<<<WB, 256, 0, stream>>>(G3, dis, row_off, csr, b3, out);
}

// Round 10
// 289.092 us; speedup vs baseline: 1.2592x; 1.0846x over previous
//
#include <hip/hip_runtime.h>
#include <hip/hip_bf16.h>
#include <math.h>

#define NN 40000
#define EE 640000
#define CSR_MAX (EE + 8 * NN)  // padded-CSR hard bound (each row pads < +8)
#define MPAD 40064             // NN rounded up to 128 for MFMA tile staging
#define LDS_STRIDE 136         // bf16 elems per LDS row (128 + 8 pad)

typedef short bf16x8 __attribute__((ext_vector_type(8)));
typedef float f32x16 __attribute__((ext_vector_type(16)));

// ---- bf16 helpers ---------------------------------------------------------
__device__ __forceinline__ unsigned bf16rne(float x) {
  unsigned u = __float_as_uint(x);
  return (u + 0x7fffu + ((u >> 16) & 1u)) >> 16;
}
__device__ __forceinline__ unsigned packbf2(float lo, float hi) {
  return bf16rne(lo) | (bf16rne(hi) << 16);
}
__device__ __forceinline__ float bflo(unsigned u) {
  return __uint_as_float(u << 16);
}
__device__ __forceinline__ float bfhi(unsigned u) {
  return __uint_as_float(u & 0xffff0000u);
}

// ---------------------------------------------------------------------------
// in-degree counts; 4 edges/thread int4 (R6-measured config)
// ---------------------------------------------------------------------------
__global__ __launch_bounds__(256) void edge_pass1(
    const int4* __restrict__ dst4, int* __restrict__ cnt) {
  int e = blockIdx.x * 256 + threadIdx.x;
  if (e >= EE / 4) return;
  int4 d = dst4[e];
  atomicAdd(&cnt[d.x], 1);
  atomicAdd(&cnt[d.y], 1);
  atomicAdd(&cnt[d.z], 1);
  atomicAdd(&cnt[d.w], 1);
}

// ---------------------------------------------------------------------------
// single-block chunked coalesced scan over PADDED degrees: row_off/cursor are
// offsets with each row rounded up to a multiple of 8 (tail-free agg loops,
// mask-free reg scan). dis comes from the true count.
// ---------------------------------------------------------------------------
__global__ __launch_bounds__(1024) void scan_kernel(
    const int4* __restrict__ cnt4, int* __restrict__ row_off,
    int* __restrict__ cursor, float* __restrict__ dis) {
  __shared__ int wsum[16];
  __shared__ int btot;
  int t = threadIdx.x;
  int lane = t & 63, w = t >> 6;
  int running = 0;
  for (int c = 0; c < 10; c++) {
    int idx4 = c * 1024 + t;
    bool ok = idx4 * 4 < NN;
    int4 v = ok ? cnt4[idx4] : int4{0, 0, 0, 0};
    int4 p;
    p.x = (v.x + 7) & ~7;
    p.y = (v.y + 7) & ~7;
    p.z = (v.z + 7) & ~7;
    p.w = (v.w + 7) & ~7;
    int ts = p.x + p.y + p.z + p.w;
    int incl = ts;
#pragma unroll
    for (int off = 1; off < 64; off <<= 1) {
      int u = __shfl_up(incl, off, 64);
      if (lane >= off) incl += u;
    }
    if (lane == 63) wsum[w] = incl;
    __syncthreads();
    if (t < 16) {
      int x = wsum[t];
#pragma unroll
      for (int off = 1; off < 16; off <<= 1) {
        int u = __shfl_up(x, off, 64);
        if (t >= off) x += u;
      }
      wsum[t] = x;
      if (t == 15) btot = x;
    }
    __syncthreads();
    int base = running + (w ? wsum[w - 1] : 0) + (incl - ts);
    if (ok) {
      int4 r;
      r.x = base;
      r.y = base + p.x;
      r.z = r.y + p.y;
      r.w = r.z + p.z;
      ((int4*)row_off)[idx4] = r;
      ((int4*)cursor)[idx4] = r;
      float4 d;
      d.x = rsqrtf((float)(v.x + 1));
      d.y = rsqrtf((float)(v.y + 1));
      d.z = rsqrtf((float)(v.z + 1));
      d.w = rsqrtf((float)(v.w + 1));
      ((float4*)dis)[idx4] = d;
    }
    running += btot;
    __syncthreads();
  }
  if (t == 0) row_off[NN] = running;
}

// ---------------------------------------------------------------------------
// pad slots [row_off[i]+cnt[i], row_off[i+1]) <- NN (dummy -> zero table row).
// Adjacent nodes write adjacent csr regions (row_off monotone) -> coalesces.
// ---------------------------------------------------------------------------
__global__ __launch_bounds__(256) void pad_fill(
    const int* __restrict__ row_off, const int* __restrict__ cnt,
    unsigned short* __restrict__ csr) {
  int i = blockIdx.x * 256 + threadIdx.x;
  if (i >= NN) return;
  int b = row_off[i] + cnt[i], en = row_off[i + 1];
  for (int k = b; k < en; k++) csr[k] = (unsigned short)NN;
}

// ---------------------------------------------------------------------------
// CSR fill; 4 edges/thread int4; uint16 entries (R8)
// ---------------------------------------------------------------------------
__global__ __launch_bounds__(256) void fill_kernel(
    const int4* __restrict__ src4, const int4* __restrict__ dst4,
    int* __restrict__ cursor, unsigned short* __restrict__ csr) {
  int e = blockIdx.x * 256 + threadIdx.x;
  if (e >= EE / 4) return;
  int4 s = src4[e];
  int4 d = dst4[e];
  int i0 = atomicAdd(&cursor[d.x], 1);
  int i1 = atomicAdd(&cursor[d.y], 1);
  int i2 = atomicAdd(&cursor[d.z], 1);
  int i3 = atomicAdd(&cursor[d.w], 1);
  csr[i0] = (unsigned short)s.x;
  csr[i1] = (unsigned short)s.y;
  csr[i2] = (unsigned short)s.z;
  csr[i3] = (unsigned short)s.w;
}

// ---------------------------------------------------------------------------
// reg_loss via padded CSR: mask-free 8-entry compare per aligned uint4
// (dummy NN never equals j < NN)
// ---------------------------------------------------------------------------
__global__ __launch_bounds__(256) void reg_csr(
    const int* __restrict__ src, const int* __restrict__ dst,
    const int* __restrict__ row_off, const unsigned short* __restrict__ csr,
    float* __restrict__ out_scalar, int E) {
  int e = blockIdx.x * 256 + threadIdx.x;
  int c = 0;
  if (e < E) {
    int i = src[e];
    unsigned j = (unsigned)dst[e];
    int q0 = row_off[i] >> 3, q1 = row_off[i + 1] >> 3;
    const uint4* base = (const uint4*)csr;
    for (int q = q0; q < q1; q++) {
      uint4 v = base[q];
      c += ((v.x & 0xffffu) == j) + ((v.x >> 16) == j);
      c += ((v.y & 0xffffu) == j) + ((v.y >> 16) == j);
      c += ((v.z & 0xffffu) == j) + ((v.z >> 16) == j);
      c += ((v.w & 0xffffu) == j) + ((v.w >> 16) == j);
    }
  }
  float v = (float)c;
  for (int off = 32; off; off >>= 1) v += __shfl_down(v, off, 64);
  __shared__ float ws[4];
  int lane = threadIdx.x & 63, w = threadIdx.x >> 6;
  if (lane == 0) ws[w] = v;
  __syncthreads();
  if (threadIdx.x == 0) atomicAdd(out_scalar, ws[0] + ws[1] + ws[2] + ws[3]);
}

// ---------------------------------------------------------------------------
// merged conversions: blocks [0,2500) X->bf16*dis ; [2500,2564) W1t ;
// [2564,2628) W2t ; [2628,2660) W3t (64x128, rows 40..63 zero) ;
// block 2660 zeroes dummy row NN of Xb and H1b.
// ---------------------------------------------------------------------------
__global__ __launch_bounds__(256) void cvt_all(
    const float4* __restrict__ X, const float* __restrict__ dis,
    uint2* __restrict__ Xb, const float* __restrict__ W1,
    const float* __restrict__ W2, const float* __restrict__ W3,
    unsigned short* __restrict__ Wt1, unsigned short* __restrict__ Wt2,
    unsigned short* __restrict__ W3t, unsigned* __restrict__ H1b) {
  int blk = blockIdx.x, t = threadIdx.x;
  if (blk < 2500) {
    int i = blk * 256 + t;
    float di = dis[i >> 4];
    float4 a = X[i * 2], b = X[i * 2 + 1];
    uint2 o;
    o.x = packbf2(di * a.x, di * a.y);
    o.y = packbf2(di * a.z, di * a.w);
    Xb[i * 2] = o;
    uint2 p;
    p.x = packbf2(di * b.x, di * b.y);
    p.y = packbf2(di * b.z, di * b.w);
    Xb[i * 2 + 1] = p;
  } else if (blk < 2628) {
    bool is1 = blk < 2564;
    int n = (blk - (is1 ? 2500 : 2564)) * 2 + (t >> 7);
    int k = t & 127;
    const float* W = is1 ? W1 : W2;
    unsigned short* Wt = is1 ? Wt1 : Wt2;
    Wt[n * 128 + k] = (unsigned short)bf16rne(W[k * 128 + n]);
  } else if (blk < 2660) {
    int n = (blk - 2628) * 2 + (t >> 7);
    int k = t & 127;
    float v = (n < 40) ? W3[k * 40 + n] : 0.f;
    W3t[n * 128 + k] = (unsigned short)bf16rne(v);
  } else {
    if (t < 64) ((unsigned*)Xb)[(size_t)NN * 64 + t] = 0u;
    else if (t < 128) H1b[(size_t)NN * 64 + (t - 64)] = 0u;
  }
}

// ---------------------------------------------------------------------------
// 128-wide aggregation over padded CSR: one uint4 csr load per 8 edges,
// 8 independent 256B gathers in flight, no tail (dummies hit zero row NN).
// ---------------------------------------------------------------------------
__global__ __launch_bounds__(256) void agg128b(
    const unsigned* __restrict__ Hb, const float* __restrict__ dis,
    const int* __restrict__ row_off, const unsigned short* __restrict__ csr,
    unsigned* __restrict__ outB) {
  int node = __builtin_amdgcn_readfirstlane(blockIdx.x * 4 + (threadIdx.x >> 6));
  int lane = threadIdx.x & 63;
  float di = dis[node];
  unsigned v = Hb[(size_t)node * 64 + lane];
  float a0 = bflo(v), a1 = bfhi(v);
  int beg = row_off[node], end = row_off[node + 1];
  for (int e = beg; e < end; e += 8) {
    uint4 cs = *(const uint4*)&csr[e];
    int s0 = cs.x & 0xffff, s1 = cs.x >> 16;
    int s2 = cs.y & 0xffff, s3 = cs.y >> 16;
    int s4 = cs.z & 0xffff, s5 = cs.z >> 16;
    int s6 = cs.w & 0xffff, s7 = cs.w >> 16;
    unsigned u0 = Hb[(size_t)s0 * 64 + lane];
    unsigned u1 = Hb[(size_t)s1 * 64 + lane];
    unsigned u2 = Hb[(size_t)s2 * 64 + lane];
    unsigned u3 = Hb[(size_t)s3 * 64 + lane];
    unsigned u4 = Hb[(size_t)s4 * 64 + lane];
    unsigned u5 = Hb[(size_t)s5 * 64 + lane];
    unsigned u6 = Hb[(size_t)s6 * 64 + lane];
    unsigned u7 = Hb[(size_t)s7 * 64 + lane];
    a0 += bflo(u0); a1 += bfhi(u0);
    a0 += bflo(u1); a1 += bfhi(u1);
    a0 += bflo(u2); a1 += bfhi(u2);
    a0 += bflo(u3); a1 += bfhi(u3);
    a0 += bflo(u4); a1 += bfhi(u4);
    a0 += bflo(u5); a1 += bfhi(u5);
    a0 += bflo(u6); a1 += bfhi(u6);
    a0 += bflo(u7); a1 += bfhi(u7);
  }
  outB[(size_t)node * 64 + lane] = packbf2(di * a0, di * a1);
}

// ---------------------------------------------------------------------------
// MFMA bf16 GEMM layer-1 (R5 structure); epilogue -> dis-scaled bf16 table
// ---------------------------------------------------------------------------
__global__ __launch_bounds__(256) void gemm_mfma(
    const unsigned* __restrict__ Ab, const unsigned* __restrict__ Wt,
    const float* __restrict__ bias, const float* __restrict__ dis,
    unsigned short* __restrict__ outB) {
  __shared__ unsigned short At[128 * LDS_STRIDE];
  __shared__ unsigned short Bt[128 * LDS_STRIDE];
  int t = threadIdx.x;
  int rowBase = blockIdx.x * 128;
  {
    const uint4* ga = (const uint4*)(Ab + (size_t)rowBase * 64);
    const uint4* gw = (const uint4*)Wt;
#pragma unroll
    for (int i = 0; i < 8; i++) {
      int idx = i * 256 + t;
      int r = idx >> 4, c = idx & 15;
      uint4 va = ga[idx];
      uint4 vw = gw[idx];
      *(uint4*)&At[r * LDS_STRIDE + c * 8] = va;
      *(uint4*)&Bt[r * LDS_STRIDE + c * 8] = vw;
    }
  }
  __syncthreads();
  int lane = t & 63, w = t >> 6;
  int m31 = lane & 31;
  int khalf = (lane >> 5) * 8;
  f32x16 acc[4] = {};
#pragma unroll
  for (int ks = 0; ks < 8; ks++) {
    bf16x8 a = *(bf16x8*)&At[(w * 32 + m31) * LDS_STRIDE + ks * 16 + khalf];
#pragma unroll
    for (int nt = 0; nt < 4; nt++) {
      bf16x8 b = *(bf16x8*)&Bt[(nt * 32 + m31) * LDS_STRIDE + ks * 16 + khalf];
      acc[nt] = __builtin_amdgcn_mfma_f32_32x32x16_bf16(a, b, acc[nt], 0, 0, 0);
    }
  }
  int rsel = (lane >> 5) * 4;
#pragma unroll
  for (int nt = 0; nt < 4; nt++) {
    int col = nt * 32 + m31;
    float bv = bias[col];
#pragma unroll
    for (int r = 0; r < 16; r++) {
      int row = rowBase + w * 32 + (r & 3) + 8 * (r >> 2) + rsel;
      if (row < NN) {
        float x = fmaxf(acc[nt][r] + bv, 0.f);
        outB[(size_t)row * 128 + col] = (unsigned short)bf16rne(dis[row] * x);
      }
    }
  }
}

// ---------------------------------------------------------------------------
// Fused layer-2 + layer-3 GEMM (R8): phase1 relu(A@W2+b2) kept in regs;
// bf16(dis*h2) -> At; W3t -> Bt; phase2 MFMA -> G3. Block 0 zeroes G3 dummy
// row NN for agg40's padded gathers.
// ---------------------------------------------------------------------------
__global__ __launch_bounds__(256) void gemm_mfma2(
    const unsigned* __restrict__ Ab, const unsigned* __restrict__ Wt,
    const float* __restrict__ bias, const float* __restrict__ dis,
    const unsigned short* __restrict__ W3t, float* __restrict__ G3) {
  __shared__ unsigned short At[128 * LDS_STRIDE];
  __shared__ unsigned short Bt[128 * LDS_STRIDE];
  __shared__ float dsh[128];
  int t = threadIdx.x;
  int rowBase = blockIdx.x * 128;
  if (blockIdx.x == 0 && t < 40) G3[(size_t)NN * 40 + t] = 0.f;
  if (t < 128) {
    int rr = rowBase + t;
    dsh[t] = (rr < NN) ? dis[rr] : 0.f;
  }
  {
    const uint4* ga = (const uint4*)(Ab + (size_t)rowBase * 64);
    const uint4* gw = (const uint4*)Wt;
#pragma unroll
    for (int i = 0; i < 8; i++) {
      int idx = i * 256 + t;
      int r = idx >> 4, c = idx & 15;
      uint4 va = ga[idx];
      uint4 vw = gw[idx];
      *(uint4*)&At[r * LDS_STRIDE + c * 8] = va;
      *(uint4*)&Bt[r * LDS_STRIDE + c * 8] = vw;
    }
  }
  __syncthreads();
  int lane = t & 63, w = t >> 6;
  int m31 = lane & 31;
  int khalf = (lane >> 5) * 8;
  f32x16 acc[4] = {};
#pragma unroll
  for (int ks = 0; ks < 8; ks++) {
    bf16x8 a = *(bf16x8*)&At[(w * 32 + m31) * LDS_STRIDE + ks * 16 + khalf];
#pragma unroll
    for (int nt = 0; nt < 4; nt++) {
      bf16x8 b = *(bf16x8*)&Bt[(nt * 32 + m31) * LDS_STRIDE + ks * 16 + khalf];
      acc[nt] = __builtin_amdgcn_mfma_f32_32x32x16_bf16(a, b, acc[nt], 0, 0, 0);
    }
  }
  __syncthreads();
  int rsel = (lane >> 5) * 4;
#pragma unroll
  for (int nt = 0; nt < 4; nt++) {
    int col = nt * 32 + m31;
    float bv = bias[col];
#pragma unroll
    for (int r = 0; r < 16; r++) {
      int rl = w * 32 + (r & 3) + 8 * (r >> 2) + rsel;
      float x = fmaxf(acc[nt][r] + bv, 0.f);
      At[rl * LDS_STRIDE + col] = (unsigned short)bf16rne(dsh[rl] * x);
    }
  }
  {
    const uint4* gw3 = (const uint4*)W3t;
#pragma unroll
    for (int i = 0; i < 4; i++) {
      int idx = i * 256 + t;
      int r = idx >> 4, c = idx & 15;
      *(uint4*)&Bt[r * LDS_STRIDE + c * 8] = gw3[idx];
    }
  }
  __syncthreads();
  f32x16 acc2[2] = {};
#pragma unroll
  for (int ks = 0; ks < 8; ks++) {
    bf16x8 a = *(bf16x8*)&At[(w * 32 + m31) * LDS_STRIDE + ks * 16 + khalf];
#pragma unroll
    for (int nt = 0; nt < 2; nt++) {
      bf16x8 b = *(bf16x8*)&Bt[(nt * 32 + m31) * LDS_STRIDE + ks * 16 + khalf];
      acc2[nt] = __builtin_amdgcn_mfma_f32_32x32x16_bf16(a, b, acc2[nt], 0, 0, 0);
    }
  }
#pragma unroll
  for (int nt = 0; nt < 2; nt++) {
    int col = nt * 32 + m31;
    if (col < 40) {
#pragma unroll
      for (int r = 0; r < 16; r++) {
        int row = rowBase + w * 32 + (r & 3) + 8 * (r >> 2) + rsel;
        if (row < NN) G3[(size_t)row * 40 + col] = acc2[nt][r];
      }
    }
  }
}

// ---------------------------------------------------------------------------
// fused 40-wide aggregation + bias + log_softmax over padded CSR
// (8 independent gathers per uint4 csr load, no tail)
// ---------------------------------------------------------------------------
__global__ __launch_bounds__(256) void agg40_softmax(
    const float* __restrict__ G, const float* __restrict__ dis,
    const int* __restrict__ row_off, const unsigned short* __restrict__ csr,
    const float* __restrict__ b3, float* __restrict__ outp) {
  int node = __builtin_amdgcn_readfirstlane(blockIdx.x * 4 + (threadIdx.x >> 6));
  int lane = threadIdx.x & 63;
  int cl = lane < 40 ? lane : 39;
  float di = dis[node];
  float a = G[(size_t)node * 40 + cl];
  int beg = row_off[node], end = row_off[node + 1];
  for (int e = beg; e < end; e += 8) {
    uint4 cs = *(const uint4*)&csr[e];
    int s0 = cs.x & 0xffff, s1 = cs.x >> 16;
    int s2 = cs.y & 0xffff, s3 = cs.y >> 16;
    int s4 = cs.z & 0xffff, s5 = cs.z >> 16;
    int s6 = cs.w & 0xffff, s7 = cs.w >> 16;
    float g0 = G[(size_t)s0 * 40 + cl];
    float g1 = G[(size_t)s1 * 40 + cl];
    float g2 = G[(size_t)s2 * 40 + cl];
    float g3 = G[(size_t)s3 * 40 + cl];
    float g4 = G[(size_t)s4 * 40 + cl];
    float g5 = G[(size_t)s5 * 40 + cl];
    float g6 = G[(size_t)s6 * 40 + cl];
    float g7 = G[(size_t)s7 * 40 + cl];
    a += g0 + g1 + g2 + g3 + g4 + g5 + g6 + g7;
  }
  float o = di * a + b3[cl];
  float m = (lane < 40) ? o : -1e30f;
  for (int off = 32; off; off >>= 1) m = fmaxf(m, __shfl_xor(m, off, 64));
  float ex = (lane < 40) ? expf(o - m) : 0.f;
  float ssum = ex;
  for (int off = 32; off; off >>= 1) ssum += __shfl_xor(ssum, off, 64);
  float res = o - m - logf(ssum);
  if (lane < 40) outp[(size_t)node * 40 + lane] = res;
}

// ---------------------------------------------------------------------------
extern "C" void kernel_launch(void* const* d_in, const int* in_sizes, int n_in,
                              void* d_out, int out_size, void* d_ws,
                              size_t ws_size, hipStream_t stream) {
  const float* X = (const float*)d_in[0];
  const int* ei = (const int*)d_in[1];
  const float* W1 = (const float*)d_in[2];
  const float* b1 = (const float*)d_in[3];
  const float* W2 = (const float*)d_in[4];
  const float* b2 = (const float*)d_in[5];
  const float* W3 = (const float*)d_in[6];
  const float* b3 = (const float*)d_in[7];
  float* out = (float*)d_out;

  const int E = EE;
  const int* src = ei;
  const int* dst = ei + E;

  char* w = (char*)d_ws;
  auto carve = [&](size_t bytes) {
    char* p = w;
    w += (bytes + 255) & ~(size_t)255;
    return p;
  };
  int* cnt = (int*)carve(NN * 4);
  float* dis = (float*)carve(NN * 4);
  int* row_off = (int*)carve((NN + 1) * 4);
  int* cursor = (int*)carve(NN * 4);
  unsigned short* csr = (unsigned short*)carve((size_t)CSR_MAX * 2);
  unsigned short* Wt1 = (unsigned short*)carve(128 * 128 * 2);
  unsigned short* Wt2 = (unsigned short*)carve(128 * 128 * 2);
  unsigned short* W3t = (unsigned short*)carve(64 * 128 * 2);
  unsigned* Ab = (unsigned*)carve((size_t)MPAD * 128 * 2);       // 10.26 MB
  char* blk = carve(((size_t)NN + 1) * 128 * 4);                 // 20.5 MB
  unsigned* Xb = (unsigned*)blk;                                 // T(X), +row NN
  unsigned* H1b = (unsigned*)(blk + ((size_t)NN + 1) * 128 * 2); // T(h1), +row NN
  float* G3 = (float*)blk;  // layer-3 pre-agg [NN+1][40]; Xb dead by then

  hipMemsetAsync(cnt, 0, NN * 4, stream);
  hipMemsetAsync((char*)d_out + (size_t)NN * 40 * 4, 0, 4, stream);

  const int E4B = (EE / 4 + 255) / 256;  // 625
  const int EB = (EE + 255) / 256;       // 2500
  const int NB = (NN + 255) / 256;       // 157
  const int WB = NN / 4;                 // 10000
  const int GB = MPAD / 128;             // 313

  edge_pass1<<<E4B, 256, 0, stream>>>((const int4*)dst, cnt);
  scan_kernel<<<1, 1024, 0, stream>>>((const int4*)cnt, row_off, cursor, dis);
  pad_fill<<<NB, 256, 0, stream>>>(row_off, cnt, csr);
  fill_kernel<<<E4B, 256, 0, stream>>>((const int4*)src, (const int4*)dst,
                                       cursor, csr);
  reg_csr<<<EB, 256, 0, stream>>>(src, dst, row_off, csr,
                                  out + (size_t)NN * 40, E);

  cvt_all<<<2661, 256, 0, stream>>>((const float4*)X, dis, (uint2*)Xb, W1, W2,
                                    W3, Wt1, Wt2, W3t, H1b);
  // layer 1: agg(T(X)) -> Ab bf16 ; MFMA gemm+relu -> T(h1) bf16
  agg128b<<<WB, 256, 0, stream>>>(Xb, dis, row_off, csr, Ab);
  gemm_mfma<<<GB, 256, 0, stream>>>(Ab, (const unsigned*)Wt1, b1, dis,
                                    (unsigned short*)H1b);
  // layer 2: agg(T(h1)) -> Ab bf16 ; fused MFMA (W2 then W3) -> G3
  agg128b<<<WB, 256, 0, stream>>>(H1b, dis, row_off, csr, Ab);
  gemm_mfma2<<<GB, 256, 0, stream>>>(Ab, (const unsigned*)Wt2, b2, dis, W3t,
                                     G3);
  // layer 3 aggregation + bias + log_softmax -> out
  agg40_softmax<<<WB, 256, 0, stream>>>(G3, dis, row_off, csr, b3, out);
}

// Round 11
// 278.768 us; speedup vs baseline: 1.3059x; 1.0370x over previous
//
#include <hip/hip_runtime.h>
#include <hip/hip_bf16.h>
#include <math.h>

#define NN 40000
#define EE 640000
#define CSR_MAX (EE + 8 * NN)  // padded-CSR hard bound (each row pads < +8)
#define MPAD 40064             // NN rounded up to 128 for MFMA tile staging
#define LDS_STRIDE 136         // bf16 elems per LDS row (128 + 8 pad)

typedef short bf16x8 __attribute__((ext_vector_type(8)));
typedef float f32x16 __attribute__((ext_vector_type(16)));

// ---- bf16 helpers ---------------------------------------------------------
__device__ __forceinline__ unsigned bf16rne(float x) {
  unsigned u = __float_as_uint(x);
  return (u + 0x7fffu + ((u >> 16) & 1u)) >> 16;
}
__device__ __forceinline__ unsigned packbf2(float lo, float hi) {
  return bf16rne(lo) | (bf16rne(hi) << 16);
}
__device__ __forceinline__ float bflo(unsigned u) {
  return __uint_as_float(u << 16);
}
__device__ __forceinline__ float bfhi(unsigned u) {
  return __uint_as_float(u & 0xffff0000u);
}

// ---------------------------------------------------------------------------
// in-degree counts; 4 edges/thread int4 (R6-measured config)
// ---------------------------------------------------------------------------
__global__ __launch_bounds__(256) void edge_pass1(
    const int4* __restrict__ dst4, int* __restrict__ cnt) {
  int e = blockIdx.x * 256 + threadIdx.x;
  if (e >= EE / 4) return;
  int4 d = dst4[e];
  atomicAdd(&cnt[d.x], 1);
  atomicAdd(&cnt[d.y], 1);
  atomicAdd(&cnt[d.z], 1);
  atomicAdd(&cnt[d.w], 1);
}

// ---------------------------------------------------------------------------
// single-block chunked coalesced scan over PADDED degrees (rows rounded to
// x8); also emits cursor(=row_off) and dis from true counts.
// ---------------------------------------------------------------------------
__global__ __launch_bounds__(1024) void scan_kernel(
    const int4* __restrict__ cnt4, int* __restrict__ row_off,
    int* __restrict__ cursor, float* __restrict__ dis) {
  __shared__ int wsum[16];
  __shared__ int btot;
  int t = threadIdx.x;
  int lane = t & 63, w = t >> 6;
  int running = 0;
  for (int c = 0; c < 10; c++) {
    int idx4 = c * 1024 + t;
    bool ok = idx4 * 4 < NN;
    int4 v = ok ? cnt4[idx4] : int4{0, 0, 0, 0};
    int4 p;
    p.x = (v.x + 7) & ~7;
    p.y = (v.y + 7) & ~7;
    p.z = (v.z + 7) & ~7;
    p.w = (v.w + 7) & ~7;
    int ts = p.x + p.y + p.z + p.w;
    int incl = ts;
#pragma unroll
    for (int off = 1; off < 64; off <<= 1) {
      int u = __shfl_up(incl, off, 64);
      if (lane >= off) incl += u;
    }
    if (lane == 63) wsum[w] = incl;
    __syncthreads();
    if (t < 16) {
      int x = wsum[t];
#pragma unroll
      for (int off = 1; off < 16; off <<= 1) {
        int u = __shfl_up(x, off, 64);
        if (t >= off) x += u;
      }
      wsum[t] = x;
      if (t == 15) btot = x;
    }
    __syncthreads();
    int base = running + (w ? wsum[w - 1] : 0) + (incl - ts);
    if (ok) {
      int4 r;
      r.x = base;
      r.y = base + p.x;
      r.z = r.y + p.y;
      r.w = r.z + p.z;
      ((int4*)row_off)[idx4] = r;
      ((int4*)cursor)[idx4] = r;
      float4 d;
      d.x = rsqrtf((float)(v.x + 1));
      d.y = rsqrtf((float)(v.y + 1));
      d.z = rsqrtf((float)(v.z + 1));
      d.w = rsqrtf((float)(v.w + 1));
      ((float4*)dis)[idx4] = d;
    }
    running += btot;
    __syncthreads();
  }
  if (t == 0) row_off[NN] = running;
}

// ---------------------------------------------------------------------------
// CSR fill (blocks < E4B) + pad fill (remaining blocks): pads and real
// entries occupy disjoint csr ranges, both depend only on scan.
// ---------------------------------------------------------------------------
#define E4B 625  // EE/4/256
__global__ __launch_bounds__(256) void fill_kernel(
    const int4* __restrict__ src4, const int4* __restrict__ dst4,
    int* __restrict__ cursor, const int* __restrict__ row_off,
    const int* __restrict__ cnt, unsigned short* __restrict__ csr) {
  int blk = blockIdx.x;
  if (blk < E4B) {
    int e = blk * 256 + threadIdx.x;
    if (e >= EE / 4) return;
    int4 s = src4[e];
    int4 d = dst4[e];
    int i0 = atomicAdd(&cursor[d.x], 1);
    int i1 = atomicAdd(&cursor[d.y], 1);
    int i2 = atomicAdd(&cursor[d.z], 1);
    int i3 = atomicAdd(&cursor[d.w], 1);
    csr[i0] = (unsigned short)s.x;
    csr[i1] = (unsigned short)s.y;
    csr[i2] = (unsigned short)s.z;
    csr[i3] = (unsigned short)s.w;
  } else {
    int i = (blk - E4B) * 256 + threadIdx.x;
    if (i >= NN) return;
    int b = row_off[i] + cnt[i], en = row_off[i + 1];
    for (int k = b; k < en; k++) csr[k] = (unsigned short)NN;
  }
}

// ---------------------------------------------------------------------------
// reg_loss via padded CSR: mask-free 8-entry compare per aligned uint4
// ---------------------------------------------------------------------------
__global__ __launch_bounds__(256) void reg_csr(
    const int* __restrict__ src, const int* __restrict__ dst,
    const int* __restrict__ row_off, const unsigned short* __restrict__ csr,
    float* __restrict__ out_scalar, int E) {
  int e = blockIdx.x * 256 + threadIdx.x;
  int c = 0;
  if (e < E) {
    int i = src[e];
    unsigned j = (unsigned)dst[e];
    int q0 = row_off[i] >> 3, q1 = row_off[i + 1] >> 3;
    const uint4* base = (const uint4*)csr;
    for (int q = q0; q < q1; q++) {
      uint4 v = base[q];
      c += ((v.x & 0xffffu) == j) + ((v.x >> 16) == j);
      c += ((v.y & 0xffffu) == j) + ((v.y >> 16) == j);
      c += ((v.z & 0xffffu) == j) + ((v.z >> 16) == j);
      c += ((v.w & 0xffffu) == j) + ((v.w >> 16) == j);
    }
  }
  float v = (float)c;
  for (int off = 32; off; off >>= 1) v += __shfl_down(v, off, 64);
  __shared__ float ws[4];
  int lane = threadIdx.x & 63, w = threadIdx.x >> 6;
  if (lane == 0) ws[w] = v;
  __syncthreads();
  if (threadIdx.x == 0) atomicAdd(out_scalar, ws[0] + ws[1] + ws[2] + ws[3]);
}

// ---------------------------------------------------------------------------
// merged conversions: blocks [0,2500) X->bf16*dis ; [2500,2564) W1t ;
// [2564,2628) W2t ; [2628,2660) W3t (64x128, rows 40..63 zero) ;
// block 2660 zeroes dummy row NN of Xb and H1b.
// ---------------------------------------------------------------------------
__global__ __launch_bounds__(256) void cvt_all(
    const float4* __restrict__ X, const float* __restrict__ dis,
    uint2* __restrict__ Xb, const float* __restrict__ W1,
    const float* __restrict__ W2, const float* __restrict__ W3,
    unsigned short* __restrict__ Wt1, unsigned short* __restrict__ Wt2,
    unsigned short* __restrict__ W3t, unsigned* __restrict__ H1b) {
  int blk = blockIdx.x, t = threadIdx.x;
  if (blk < 2500) {
    int i = blk * 256 + t;
    float di = dis[i >> 4];
    float4 a = X[i * 2], b = X[i * 2 + 1];
    uint2 o;
    o.x = packbf2(di * a.x, di * a.y);
    o.y = packbf2(di * a.z, di * a.w);
    Xb[i * 2] = o;
    uint2 p;
    p.x = packbf2(di * b.x, di * b.y);
    p.y = packbf2(di * b.z, di * b.w);
    Xb[i * 2 + 1] = p;
  } else if (blk < 2628) {
    bool is1 = blk < 2564;
    int n = (blk - (is1 ? 2500 : 2564)) * 2 + (t >> 7);
    int k = t & 127;
    const float* W = is1 ? W1 : W2;
    unsigned short* Wt = is1 ? Wt1 : Wt2;
    Wt[n * 128 + k] = (unsigned short)bf16rne(W[k * 128 + n]);
  } else if (blk < 2660) {
    int n = (blk - 2628) * 2 + (t >> 7);
    int k = t & 127;
    float v = (n < 40) ? W3[k * 40 + n] : 0.f;
    W3t[n * 128 + k] = (unsigned short)bf16rne(v);
  } else {
    if (t < 64) ((unsigned*)Xb)[(size_t)NN * 64 + t] = 0u;
    else if (t < 128) H1b[(size_t)NN * 64 + (t - 64)] = 0u;
  }
}

// ---------------------------------------------------------------------------
// 128-wide aggregation over padded CSR, 8 gathers in flight per iter, with
// the wave-uniform csr uint4 PREFETCHED one iteration ahead (keeps the
// scalar load off the gather critical path).
// ---------------------------------------------------------------------------
__global__ __launch_bounds__(256) void agg128b(
    const unsigned* __restrict__ Hb, const float* __restrict__ dis,
    const int* __restrict__ row_off, const unsigned short* __restrict__ csr,
    unsigned* __restrict__ outB) {
  int node = __builtin_amdgcn_readfirstlane(blockIdx.x * 4 + (threadIdx.x >> 6));
  int lane = threadIdx.x & 63;
  float di = dis[node];
  unsigned v = Hb[(size_t)node * 64 + lane];
  float a0 = bflo(v), a1 = bfhi(v);
  int beg = row_off[node], end = row_off[node + 1];
  if (beg < end) {
    uint4 cs = *(const uint4*)&csr[beg];
    for (int e = beg; e < end; e += 8) {
      int s0 = cs.x & 0xffff, s1 = cs.x >> 16;
      int s2 = cs.y & 0xffff, s3 = cs.y >> 16;
      int s4 = cs.z & 0xffff, s5 = cs.z >> 16;
      int s6 = cs.w & 0xffff, s7 = cs.w >> 16;
      unsigned u0 = Hb[(size_t)s0 * 64 + lane];
      unsigned u1 = Hb[(size_t)s1 * 64 + lane];
      unsigned u2 = Hb[(size_t)s2 * 64 + lane];
      unsigned u3 = Hb[(size_t)s3 * 64 + lane];
      unsigned u4 = Hb[(size_t)s4 * 64 + lane];
      unsigned u5 = Hb[(size_t)s5 * 64 + lane];
      unsigned u6 = Hb[(size_t)s6 * 64 + lane];
      unsigned u7 = Hb[(size_t)s7 * 64 + lane];
      if (e + 8 < end) cs = *(const uint4*)&csr[e + 8];
      a0 += bflo(u0); a1 += bfhi(u0);
      a0 += bflo(u1); a1 += bfhi(u1);
      a0 += bflo(u2); a1 += bfhi(u2);
      a0 += bflo(u3); a1 += bfhi(u3);
      a0 += bflo(u4); a1 += bfhi(u4);
      a0 += bflo(u5); a1 += bfhi(u5);
      a0 += bflo(u6); a1 += bfhi(u6);
      a0 += bflo(u7); a1 += bfhi(u7);
    }
  }
  outB[(size_t)node * 64 + lane] = packbf2(di * a0, di * a1);
}

// ---------------------------------------------------------------------------
// MFMA bf16 GEMM layer-1; epilogue repacks the C-tile through LDS (At is
// dead after the MFMA phase) and emits coalesced uint4 stores.
// ---------------------------------------------------------------------------
__global__ __launch_bounds__(256) void gemm_mfma(
    const unsigned* __restrict__ Ab, const unsigned* __restrict__ Wt,
    const float* __restrict__ bias, const float* __restrict__ dis,
    unsigned short* __restrict__ outB) {
  __shared__ unsigned short At[128 * LDS_STRIDE];
  __shared__ unsigned short Bt[128 * LDS_STRIDE];
  __shared__ float dsh[128];
  int t = threadIdx.x;
  int rowBase = blockIdx.x * 128;
  if (t < 128) {
    int rr = rowBase + t;
    dsh[t] = (rr < NN) ? dis[rr] : 0.f;
  }
  {
    const uint4* ga = (const uint4*)(Ab + (size_t)rowBase * 64);
    const uint4* gw = (const uint4*)Wt;
#pragma unroll
    for (int i = 0; i < 8; i++) {
      int idx = i * 256 + t;
      int r = idx >> 4, c = idx & 15;
      uint4 va = ga[idx];
      uint4 vw = gw[idx];
      *(uint4*)&At[r * LDS_STRIDE + c * 8] = va;
      *(uint4*)&Bt[r * LDS_STRIDE + c * 8] = vw;
    }
  }
  __syncthreads();
  int lane = t & 63, w = t >> 6;
  int m31 = lane & 31;
  int khalf = (lane >> 5) * 8;
  f32x16 acc[4] = {};
#pragma unroll
  for (int ks = 0; ks < 8; ks++) {
    bf16x8 a = *(bf16x8*)&At[(w * 32 + m31) * LDS_STRIDE + ks * 16 + khalf];
#pragma unroll
    for (int nt = 0; nt < 4; nt++) {
      bf16x8 b = *(bf16x8*)&Bt[(nt * 32 + m31) * LDS_STRIDE + ks * 16 + khalf];
      acc[nt] = __builtin_amdgcn_mfma_f32_32x32x16_bf16(a, b, acc[nt], 0, 0, 0);
    }
  }
  __syncthreads();  // At dead; reuse as bf16 C-tile staging
  int rsel = (lane >> 5) * 4;
#pragma unroll
  for (int nt = 0; nt < 4; nt++) {
    int col = nt * 32 + m31;
    float bv = bias[col];
#pragma unroll
    for (int r = 0; r < 16; r++) {
      int rl = w * 32 + (r & 3) + 8 * (r >> 2) + rsel;
      float x = fmaxf(acc[nt][r] + bv, 0.f);
      At[rl * LDS_STRIDE + col] = (unsigned short)bf16rne(dsh[rl] * x);
    }
  }
  __syncthreads();
  // coalesced copy-out: 128 rows x 16 uint4
  {
#pragma unroll
    for (int i = 0; i < 8; i++) {
      int idx = i * 256 + t;
      int r = idx >> 4, c = idx & 15;
      int grow = rowBase + r;
      if (grow < NN) {
        uint4 vv = *(const uint4*)&At[r * LDS_STRIDE + c * 8];
        *(uint4*)&outB[(size_t)grow * 128 + c * 8] = vv;
      }
    }
  }
}

// ---------------------------------------------------------------------------
// Fused layer-2 + layer-3 GEMM; phase1 relu(A@W2+b2) in regs -> bf16 At;
// phase2 (dis*h2)@W3 -> fp32 staged in LDS -> fully-contiguous float4 copy
// to G3.
// ---------------------------------------------------------------------------
__global__ __launch_bounds__(256) void gemm_mfma2(
    const unsigned* __restrict__ Ab, const unsigned* __restrict__ Wt,
    const float* __restrict__ bias, const float* __restrict__ dis,
    const unsigned short* __restrict__ W3t, float* __restrict__ G3) {
  __shared__ unsigned short At[128 * LDS_STRIDE];
  __shared__ unsigned short Bt[128 * LDS_STRIDE];
  __shared__ float dsh[128];
  int t = threadIdx.x;
  int rowBase = blockIdx.x * 128;
  if (blockIdx.x == 0 && t < 40) G3[(size_t)NN * 40 + t] = 0.f;
  if (t < 128) {
    int rr = rowBase + t;
    dsh[t] = (rr < NN) ? dis[rr] : 0.f;
  }
  {
    const uint4* ga = (const uint4*)(Ab + (size_t)rowBase * 64);
    const uint4* gw = (const uint4*)Wt;
#pragma unroll
    for (int i = 0; i < 8; i++) {
      int idx = i * 256 + t;
      int r = idx >> 4, c = idx & 15;
      uint4 va = ga[idx];
      uint4 vw = gw[idx];
      *(uint4*)&At[r * LDS_STRIDE + c * 8] = va;
      *(uint4*)&Bt[r * LDS_STRIDE + c * 8] = vw;
    }
  }
  __syncthreads();
  int lane = t & 63, w = t >> 6;
  int m31 = lane & 31;
  int khalf = (lane >> 5) * 8;
  f32x16 acc[4] = {};
#pragma unroll
  for (int ks = 0; ks < 8; ks++) {
    bf16x8 a = *(bf16x8*)&At[(w * 32 + m31) * LDS_STRIDE + ks * 16 + khalf];
#pragma unroll
    for (int nt = 0; nt < 4; nt++) {
      bf16x8 b = *(bf16x8*)&Bt[(nt * 32 + m31) * LDS_STRIDE + ks * 16 + khalf];
      acc[nt] = __builtin_amdgcn_mfma_f32_32x32x16_bf16(a, b, acc[nt], 0, 0, 0);
    }
  }
  __syncthreads();
  int rsel = (lane >> 5) * 4;
#pragma unroll
  for (int nt = 0; nt < 4; nt++) {
    int col = nt * 32 + m31;
    float bv = bias[col];
#pragma unroll
    for (int r = 0; r < 16; r++) {
      int rl = w * 32 + (r & 3) + 8 * (r >> 2) + rsel;
      float x = fmaxf(acc[nt][r] + bv, 0.f);
      At[rl * LDS_STRIDE + col] = (unsigned short)bf16rne(dsh[rl] * x);
    }
  }
  {
    const uint4* gw3 = (const uint4*)W3t;
#pragma unroll
    for (int i = 0; i < 4; i++) {
      int idx = i * 256 + t;
      int r = idx >> 4, c = idx & 15;
      *(uint4*)&Bt[r * LDS_STRIDE + c * 8] = gw3[idx];
    }
  }
  __syncthreads();
  f32x16 acc2[2] = {};
#pragma unroll
  for (int ks = 0; ks < 8; ks++) {
    bf16x8 a = *(bf16x8*)&At[(w * 32 + m31) * LDS_STRIDE + ks * 16 + khalf];
#pragma unroll
    for (int nt = 0; nt < 2; nt++) {
      bf16x8 b = *(bf16x8*)&Bt[(nt * 32 + m31) * LDS_STRIDE + ks * 16 + khalf];
      acc2[nt] = __builtin_amdgcn_mfma_f32_32x32x16_bf16(a, b, acc2[nt], 0, 0, 0);
    }
  }
  __syncthreads();  // At dead again; reuse as fp32 [128][40] staging
  float* Gst = (float*)At;
#pragma unroll
  for (int nt = 0; nt < 2; nt++) {
    int col = nt * 32 + m31;
    if (col < 40) {
#pragma unroll
      for (int r = 0; r < 16; r++) {
        int rl = w * 32 + (r & 3) + 8 * (r >> 2) + rsel;
        Gst[rl * 40 + col] = acc2[nt][r];
      }
    }
  }
  __syncthreads();
  // fully-contiguous copy-out: 128*40 floats = 1280 float4
  {
    int lim = NN - rowBase;               // valid rows this block
    int lim4 = (lim >= 128) ? 1280 : lim * 10;
#pragma unroll
    for (int i = 0; i < 5; i++) {
      int idx = i * 256 + t;
      if (idx < lim4) {
        float4 vv = *(const float4*)&Gst[idx * 4];
        *(float4*)&G3[(size_t)rowBase * 40 + idx * 4] = vv;
      }
    }
  }
}

// ---------------------------------------------------------------------------
// fused 40-wide aggregation + bias + log_softmax over padded CSR, with csr
// uint4 prefetch (same pipeline as agg128b)
// ---------------------------------------------------------------------------
__global__ __launch_bounds__(256) void agg40_softmax(
    const float* __restrict__ G, const float* __restrict__ dis,
    const int* __restrict__ row_off, const unsigned short* __restrict__ csr,
    const float* __restrict__ b3, float* __restrict__ outp) {
  int node = __builtin_amdgcn_readfirstlane(blockIdx.x * 4 + (threadIdx.x >> 6));
  int lane = threadIdx.x & 63;
  int cl = lane < 40 ? lane : 39;
  float di = dis[node];
  float a = G[(size_t)node * 40 + cl];
  int beg = row_off[node], end = row_off[node + 1];
  if (beg < end) {
    uint4 cs = *(const uint4*)&csr[beg];
    for (int e = beg; e < end; e += 8) {
      int s0 = cs.x & 0xffff, s1 = cs.x >> 16;
      int s2 = cs.y & 0xffff, s3 = cs.y >> 16;
      int s4 = cs.z & 0xffff, s5 = cs.z >> 16;
      int s6 = cs.w & 0xffff, s7 = cs.w >> 16;
      float g0 = G[(size_t)s0 * 40 + cl];
      float g1 = G[(size_t)s1 * 40 + cl];
      float g2 = G[(size_t)s2 * 40 + cl];
      float g3 = G[(size_t)s3 * 40 + cl];
      float g4 = G[(size_t)s4 * 40 + cl];
      float g5 = G[(size_t)s5 * 40 + cl];
      float g6 = G[(size_t)s6 * 40 + cl];
      float g7 = G[(size_t)s7 * 40 + cl];
      if (e + 8 < end) cs = *(const uint4*)&csr[e + 8];
      a += g0 + g1 + g2 + g3 + g4 + g5 + g6 + g7;
    }
  }
  float o = di * a + b3[cl];
  float m = (lane < 40) ? o : -1e30f;
  for (int off = 32; off; off >>= 1) m = fmaxf(m, __shfl_xor(m, off, 64));
  float ex = (lane < 40) ? expf(o - m) : 0.f;
  float ssum = ex;
  for (int off = 32; off; off >>= 1) ssum += __shfl_xor(ssum, off, 64);
  float res = o - m - logf(ssum);
  if (lane < 40) outp[(size_t)node * 40 + lane] = res;
}

// ---------------------------------------------------------------------------
extern "C" void kernel_launch(void* const* d_in, const int* in_sizes, int n_in,
                              void* d_out, int out_size, void* d_ws,
                              size_t ws_size, hipStream_t stream) {
  const float* X = (const float*)d_in[0];
  const int* ei = (const int*)d_in[1];
  const float* W1 = (const float*)d_in[2];
  const float* b1 = (const float*)d_in[3];
  const float* W2 = (const float*)d_in[4];
  const float* b2 = (const float*)d_in[5];
  const float* W3 = (const float*)d_in[6];
  const float* b3 = (const float*)d_in[7];
  float* out = (float*)d_out;

  const int E = EE;
  const int* src = ei;
  const int* dst = ei + E;

  char* w = (char*)d_ws;
  auto carve = [&](size_t bytes) {
    char* p = w;
    w += (bytes + 255) & ~(size_t)255;
    return p;
  };
  int* cnt = (int*)carve(NN * 4);
  float* dis = (float*)carve(NN * 4);
  int* row_off = (int*)carve((NN + 1) * 4);
  int* cursor = (int*)carve(NN * 4);
  unsigned short* csr = (unsigned short*)carve((size_t)CSR_MAX * 2);
  unsigned short* Wt1 = (unsigned short*)carve(128 * 128 * 2);
  unsigned short* Wt2 = (unsigned short*)carve(128 * 128 * 2);
  unsigned short* W3t = (unsigned short*)carve(64 * 128 * 2);
  unsigned* Ab = (unsigned*)carve((size_t)MPAD * 128 * 2);       // 10.26 MB
  char* blk = carve(((size_t)NN + 1) * 128 * 4);                 // 20.5 MB
  unsigned* Xb = (unsigned*)blk;                                 // T(X), +row NN
  unsigned* H1b = (unsigned*)(blk + ((size_t)NN + 1) * 128 * 2); // T(h1), +row NN
  float* G3 = (float*)blk;  // layer-3 pre-agg [NN+1][40]; Xb dead by then

  hipMemsetAsync(cnt, 0, NN * 4, stream);
  hipMemsetAsync((char*)d_out + (size_t)NN * 40 * 4, 0, 4, stream);

  const int EB = (EE + 255) / 256;  // 2500
  const int NB = (NN + 255) / 256;  // 157
  const int WB = NN / 4;            // 10000
  const int GB = MPAD / 128;        // 313

  edge_pass1<<<E4B, 256, 0, stream>>>((const int4*)dst, cnt);
  scan_kernel<<<1, 1024, 0, stream>>>((const int4*)cnt, row_off, cursor, dis);
  fill_kernel<<<E4B + NB, 256, 0, stream>>>((const int4*)src, (const int4*)dst,
                                            cursor, row_off, cnt, csr);
  reg_csr<<<EB, 256, 0, stream>>>(src, dst, row_off, csr,
                                  out + (size_t)NN * 40, E);

  cvt_all<<<2661, 256, 0, stream>>>((const float4*)X, dis, (uint2*)Xb, W1, W2,
                                    W3, Wt1, Wt2, W3t, H1b);
  // layer 1: agg(T(X)) -> Ab bf16 ; MFMA gemm+relu -> T(h1) bf16
  agg128b<<<WB, 256, 0, stream>>>(Xb, dis, row_off, csr, Ab);
  gemm_mfma<<<GB, 256, 0, stream>>>(Ab, (const unsigned*)Wt1, b1, dis,
                                    (unsigned short*)H1b);
  // layer 2: agg(T(h1)) -> Ab bf16 ; fused MFMA (W2 then W3) -> G3
  agg128b<<<WB, 256, 0, stream>>>(H1b, dis, row_off, csr, Ab);
  gemm_mfma2<<<GB, 256, 0, stream>>>(Ab, (const unsigned*)Wt2, b2, dis, W3t,
                                     G3);
  // layer 3 aggregation + bias + log_softmax -> out
  agg40_softmax<<<WB, 256, 0, stream>>>(G3, dis, row_off, csr, b3, out);
}

// Round 12
// 271.764 us; speedup vs baseline: 1.3395x; 1.0258x over previous
//
#include <hip/hip_runtime.h>
#include <hip/hip_bf16.h>
#include <math.h>

#define NN 40000
#define EE 640000
#define CSR_MAX (EE + 8 * NN)  // padded-CSR hard bound (each row pads < +8)
#define MPAD 40064             // NN rounded up to 128 for MFMA tile staging
#define LDS_STRIDE 136         // bf16 elems per LDS row (128 + 8 pad)
#define E4B 625                // EE/4/256
#define NB 157                 // ceil(NN/256)

typedef short bf16x8 __attribute__((ext_vector_type(8)));
typedef float f32x16 __attribute__((ext_vector_type(16)));

// ---- bf16 helpers ---------------------------------------------------------
__device__ __forceinline__ unsigned bf16rne(float x) {
  unsigned u = __float_as_uint(x);
  return (u + 0x7fffu + ((u >> 16) & 1u)) >> 16;
}
__device__ __forceinline__ unsigned packbf2(float lo, float hi) {
  return bf16rne(lo) | (bf16rne(hi) << 16);
}
__device__ __forceinline__ float bflo(unsigned u) {
  return __uint_as_float(u << 16);
}
__device__ __forceinline__ float bfhi(unsigned u) {
  return __uint_as_float(u & 0xffff0000u);
}

// ---------------------------------------------------------------------------
// Fused dispatch 1: edge-degree atomics (blocks <625) + W1t/W2t/W3t bf16
// transposes (blocks 625..784) + gather-table dummy-row zeroing (block 785).
// The W/zero blocks depend on nothing and backfill CUs left idle by the
// latency-bound atomic blocks.
// ---------------------------------------------------------------------------
__global__ __launch_bounds__(256) void edge_w_kernel(
    const int4* __restrict__ dst4, int* __restrict__ cnt,
    const float* __restrict__ W1, const float* __restrict__ W2,
    const float* __restrict__ W3, unsigned short* __restrict__ Wt1,
    unsigned short* __restrict__ Wt2, unsigned short* __restrict__ W3t,
    unsigned* __restrict__ Xb, unsigned* __restrict__ H1b) {
  int blk = blockIdx.x, t = threadIdx.x;
  if (blk < E4B) {
    int e = blk * 256 + t;
    int4 d = dst4[e];
    atomicAdd(&cnt[d.x], 1);
    atomicAdd(&cnt[d.y], 1);
    atomicAdd(&cnt[d.z], 1);
    atomicAdd(&cnt[d.w], 1);
  } else if (blk < 753) {
    bool is1 = blk < 689;
    int n = (blk - (is1 ? 625 : 689)) * 2 + (t >> 7);
    int k = t & 127;
    const float* W = is1 ? W1 : W2;
    unsigned short* Wt = is1 ? Wt1 : Wt2;
    Wt[n * 128 + k] = (unsigned short)bf16rne(W[k * 128 + n]);
  } else if (blk < 785) {
    int n = (blk - 753) * 2 + (t >> 7);
    int k = t & 127;
    float v = (n < 40) ? W3[k * 40 + n] : 0.f;
    W3t[n * 128 + k] = (unsigned short)bf16rne(v);
  } else {
    if (t < 64) Xb[(size_t)NN * 64 + t] = 0u;
    else if (t < 128) H1b[(size_t)NN * 64 + (t - 64)] = 0u;
  }
}

// ---------------------------------------------------------------------------
// single-block chunked coalesced scan over PADDED degrees (rows rounded to
// x8); also emits cursor(=row_off) and dis from true counts.
// ---------------------------------------------------------------------------
__global__ __launch_bounds__(1024) void scan_kernel(
    const int4* __restrict__ cnt4, int* __restrict__ row_off,
    int* __restrict__ cursor, float* __restrict__ dis) {
  __shared__ int wsum[16];
  __shared__ int btot;
  int t = threadIdx.x;
  int lane = t & 63, w = t >> 6;
  int running = 0;
  for (int c = 0; c < 10; c++) {
    int idx4 = c * 1024 + t;
    bool ok = idx4 * 4 < NN;
    int4 v = ok ? cnt4[idx4] : int4{0, 0, 0, 0};
    int4 p;
    p.x = (v.x + 7) & ~7;
    p.y = (v.y + 7) & ~7;
    p.z = (v.z + 7) & ~7;
    p.w = (v.w + 7) & ~7;
    int ts = p.x + p.y + p.z + p.w;
    int incl = ts;
#pragma unroll
    for (int off = 1; off < 64; off <<= 1) {
      int u = __shfl_up(incl, off, 64);
      if (lane >= off) incl += u;
    }
    if (lane == 63) wsum[w] = incl;
    __syncthreads();
    if (t < 16) {
      int x = wsum[t];
#pragma unroll
      for (int off = 1; off < 16; off <<= 1) {
        int u = __shfl_up(x, off, 64);
        if (t >= off) x += u;
      }
      wsum[t] = x;
      if (t == 15) btot = x;
    }
    __syncthreads();
    int base = running + (w ? wsum[w - 1] : 0) + (incl - ts);
    if (ok) {
      int4 r;
      r.x = base;
      r.y = base + p.x;
      r.z = r.y + p.y;
      r.w = r.z + p.z;
      ((int4*)row_off)[idx4] = r;
      ((int4*)cursor)[idx4] = r;
      float4 d;
      d.x = rsqrtf((float)(v.x + 1));
      d.y = rsqrtf((float)(v.y + 1));
      d.z = rsqrtf((float)(v.z + 1));
      d.w = rsqrtf((float)(v.w + 1));
      ((float4*)dis)[idx4] = d;
    }
    running += btot;
    __syncthreads();
  }
  if (t == 0) row_off[NN] = running;
}

// ---------------------------------------------------------------------------
// Fused dispatch 3: CSR fill (blocks <625) + pad fill (625..781) + X->bf16
// dis-scaled conversion (782..3281). All depend only on scan; conversion
// blocks backfill the CUs behind the atomic-latency-bound fill blocks.
// ---------------------------------------------------------------------------
__global__ __launch_bounds__(256) void fill_x_kernel(
    const int4* __restrict__ src4, const int4* __restrict__ dst4,
    int* __restrict__ cursor, const int* __restrict__ row_off,
    const int* __restrict__ cnt, unsigned short* __restrict__ csr,
    const float4* __restrict__ X, const float* __restrict__ dis,
    uint2* __restrict__ Xb) {
  int blk = blockIdx.x, t = threadIdx.x;
  if (blk < E4B) {
    int e = blk * 256 + t;
    int4 s = src4[e];
    int4 d = dst4[e];
    int i0 = atomicAdd(&cursor[d.x], 1);
    int i1 = atomicAdd(&cursor[d.y], 1);
    int i2 = atomicAdd(&cursor[d.z], 1);
    int i3 = atomicAdd(&cursor[d.w], 1);
    csr[i0] = (unsigned short)s.x;
    csr[i1] = (unsigned short)s.y;
    csr[i2] = (unsigned short)s.z;
    csr[i3] = (unsigned short)s.w;
  } else if (blk < E4B + NB) {
    int i = (blk - E4B) * 256 + t;
    if (i >= NN) return;
    int b = row_off[i] + cnt[i], en = row_off[i + 1];
    for (int k = b; k < en; k++) csr[k] = (unsigned short)NN;
  } else {
    int i = (blk - E4B - NB) * 256 + t;
    float di = dis[i >> 4];
    float4 a = X[i * 2], b = X[i * 2 + 1];
    uint2 o;
    o.x = packbf2(di * a.x, di * a.y);
    o.y = packbf2(di * a.z, di * a.w);
    Xb[i * 2] = o;
    uint2 p;
    p.x = packbf2(di * b.x, di * b.y);
    p.y = packbf2(di * b.z, di * b.w);
    Xb[i * 2 + 1] = p;
  }
}

// ---------------------------------------------------------------------------
// agg128b body (R10/R11-measured form): 8 gathers in flight, csr prefetch
// ---------------------------------------------------------------------------
__device__ __forceinline__ void agg128_body(
    int node, int lane, const unsigned* __restrict__ Hb,
    const float* __restrict__ dis, const int* __restrict__ row_off,
    const unsigned short* __restrict__ csr, unsigned* __restrict__ outB) {
  float di = dis[node];
  unsigned v = Hb[(size_t)node * 64 + lane];
  float a0 = bflo(v), a1 = bfhi(v);
  int beg = row_off[node], end = row_off[node + 1];
  if (beg < end) {
    uint4 cs = *(const uint4*)&csr[beg];
    for (int e = beg; e < end; e += 8) {
      int s0 = cs.x & 0xffff, s1 = cs.x >> 16;
      int s2 = cs.y & 0xffff, s3 = cs.y >> 16;
      int s4 = cs.z & 0xffff, s5 = cs.z >> 16;
      int s6 = cs.w & 0xffff, s7 = cs.w >> 16;
      unsigned u0 = Hb[(size_t)s0 * 64 + lane];
      unsigned u1 = Hb[(size_t)s1 * 64 + lane];
      unsigned u2 = Hb[(size_t)s2 * 64 + lane];
      unsigned u3 = Hb[(size_t)s3 * 64 + lane];
      unsigned u4 = Hb[(size_t)s4 * 64 + lane];
      unsigned u5 = Hb[(size_t)s5 * 64 + lane];
      unsigned u6 = Hb[(size_t)s6 * 64 + lane];
      unsigned u7 = Hb[(size_t)s7 * 64 + lane];
      if (e + 8 < end) cs = *(const uint4*)&csr[e + 8];
      a0 += bflo(u0); a1 += bfhi(u0);
      a0 += bflo(u1); a1 += bfhi(u1);
      a0 += bflo(u2); a1 += bfhi(u2);
      a0 += bflo(u3); a1 += bfhi(u3);
      a0 += bflo(u4); a1 += bfhi(u4);
      a0 += bflo(u5); a1 += bfhi(u5);
      a0 += bflo(u6); a1 += bfhi(u6);
      a0 += bflo(u7); a1 += bfhi(u7);
    }
  }
  outB[(size_t)node * 64 + lane] = packbf2(di * a0, di * a1);
}

// ---------------------------------------------------------------------------
// Fused dispatch 4: layer-1 aggregation (blocks <10000) + reg_loss scan
// (blocks 10000..12499). Both depend only on csr (+Xb for agg); reg blocks
// backfill as the agg wave drains.
// ---------------------------------------------------------------------------
__global__ __launch_bounds__(256) void agg1_reg(
    const unsigned* __restrict__ Xb, const float* __restrict__ dis,
    const int* __restrict__ row_off, const unsigned short* __restrict__ csr,
    unsigned* __restrict__ outB, const int* __restrict__ src,
    const int* __restrict__ dst, float* __restrict__ out_scalar) {
  int blk = blockIdx.x;
  if (blk < 10000) {
    int node = __builtin_amdgcn_readfirstlane(blk * 4 + (threadIdx.x >> 6));
    agg128_body(node, threadIdx.x & 63, Xb, dis, row_off, csr, outB);
    return;
  }
  int e = (blk - 10000) * 256 + threadIdx.x;
  int c = 0;
  {
    int i = src[e];
    unsigned j = (unsigned)dst[e];
    int q0 = row_off[i] >> 3, q1 = row_off[i + 1] >> 3;
    const uint4* base = (const uint4*)csr;
    for (int q = q0; q < q1; q++) {
      uint4 v = base[q];
      c += ((v.x & 0xffffu) == j) + ((v.x >> 16) == j);
      c += ((v.y & 0xffffu) == j) + ((v.y >> 16) == j);
      c += ((v.z & 0xffffu) == j) + ((v.z >> 16) == j);
      c += ((v.w & 0xffffu) == j) + ((v.w >> 16) == j);
    }
  }
  float v = (float)c;
  for (int off = 32; off; off >>= 1) v += __shfl_down(v, off, 64);
  __shared__ float ws[4];
  int lane = threadIdx.x & 63, w = threadIdx.x >> 6;
  if (lane == 0) ws[w] = v;
  __syncthreads();
  if (threadIdx.x == 0) atomicAdd(out_scalar, ws[0] + ws[1] + ws[2] + ws[3]);
}

// ---------------------------------------------------------------------------
// layer-2 aggregation (standalone)
// ---------------------------------------------------------------------------
__global__ __launch_bounds__(256) void agg128b(
    const unsigned* __restrict__ Hb, const float* __restrict__ dis,
    const int* __restrict__ row_off, const unsigned short* __restrict__ csr,
    unsigned* __restrict__ outB) {
  int node = __builtin_amdgcn_readfirstlane(blockIdx.x * 4 + (threadIdx.x >> 6));
  agg128_body(node, threadIdx.x & 63, Hb, dis, row_off, csr, outB);
}

// ---------------------------------------------------------------------------
// MFMA bf16 GEMM layer-1; C-tile repacked through LDS -> coalesced uint4
// ---------------------------------------------------------------------------
__global__ __launch_bounds__(256) void gemm_mfma(
    const unsigned* __restrict__ Ab, const unsigned* __restrict__ Wt,
    const float* __restrict__ bias, const float* __restrict__ dis,
    unsigned short* __restrict__ outB) {
  __shared__ unsigned short At[128 * LDS_STRIDE];
  __shared__ unsigned short Bt[128 * LDS_STRIDE];
  __shared__ float dsh[128];
  int t = threadIdx.x;
  int rowBase = blockIdx.x * 128;
  if (t < 128) {
    int rr = rowBase + t;
    dsh[t] = (rr < NN) ? dis[rr] : 0.f;
  }
  {
    const uint4* ga = (const uint4*)(Ab + (size_t)rowBase * 64);
    const uint4* gw = (const uint4*)Wt;
#pragma unroll
    for (int i = 0; i < 8; i++) {
      int idx = i * 256 + t;
      int r = idx >> 4, c = idx & 15;
      uint4 va = ga[idx];
      uint4 vw = gw[idx];
      *(uint4*)&At[r * LDS_STRIDE + c * 8] = va;
      *(uint4*)&Bt[r * LDS_STRIDE + c * 8] = vw;
    }
  }
  __syncthreads();
  int lane = t & 63, w = t >> 6;
  int m31 = lane & 31;
  int khalf = (lane >> 5) * 8;
  f32x16 acc[4] = {};
#pragma unroll
  for (int ks = 0; ks < 8; ks++) {
    bf16x8 a = *(bf16x8*)&At[(w * 32 + m31) * LDS_STRIDE + ks * 16 + khalf];
#pragma unroll
    for (int nt = 0; nt < 4; nt++) {
      bf16x8 b = *(bf16x8*)&Bt[(nt * 32 + m31) * LDS_STRIDE + ks * 16 + khalf];
      acc[nt] = __builtin_amdgcn_mfma_f32_32x32x16_bf16(a, b, acc[nt], 0, 0, 0);
    }
  }
  __syncthreads();  // At dead; reuse as bf16 C-tile staging
  int rsel = (lane >> 5) * 4;
#pragma unroll
  for (int nt = 0; nt < 4; nt++) {
    int col = nt * 32 + m31;
    float bv = bias[col];
#pragma unroll
    for (int r = 0; r < 16; r++) {
      int rl = w * 32 + (r & 3) + 8 * (r >> 2) + rsel;
      float x = fmaxf(acc[nt][r] + bv, 0.f);
      At[rl * LDS_STRIDE + col] = (unsigned short)bf16rne(dsh[rl] * x);
    }
  }
  __syncthreads();
  {
#pragma unroll
    for (int i = 0; i < 8; i++) {
      int idx = i * 256 + t;
      int r = idx >> 4, c = idx & 15;
      int grow = rowBase + r;
      if (grow < NN) {
        uint4 vv = *(const uint4*)&At[r * LDS_STRIDE + c * 8];
        *(uint4*)&outB[(size_t)grow * 128 + c * 8] = vv;
      }
    }
  }
}

// ---------------------------------------------------------------------------
// Fused layer-2 + layer-3 GEMM; phase2 result staged in LDS, contiguous
// float4 copy-out to G3.
// ---------------------------------------------------------------------------
__global__ __launch_bounds__(256) void gemm_mfma2(
    const unsigned* __restrict__ Ab, const unsigned* __restrict__ Wt,
    const float* __restrict__ bias, const float* __restrict__ dis,
    const unsigned short* __restrict__ W3t, float* __restrict__ G3) {
  __shared__ unsigned short At[128 * LDS_STRIDE];
  __shared__ unsigned short Bt[128 * LDS_STRIDE];
  __shared__ float dsh[128];
  int t = threadIdx.x;
  int rowBase = blockIdx.x * 128;
  if (blockIdx.x == 0 && t < 40) G3[(size_t)NN * 40 + t] = 0.f;
  if (t < 128) {
    int rr = rowBase + t;
    dsh[t] = (rr < NN) ? dis[rr] : 0.f;
  }
  {
    const uint4* ga = (const uint4*)(Ab + (size_t)rowBase * 64);
    const uint4* gw = (const uint4*)Wt;
#pragma unroll
    for (int i = 0; i < 8; i++) {
      int idx = i * 256 + t;
      int r = idx >> 4, c = idx & 15;
      uint4 va = ga[idx];
      uint4 vw = gw[idx];
      *(uint4*)&At[r * LDS_STRIDE + c * 8] = va;
      *(uint4*)&Bt[r * LDS_STRIDE + c * 8] = vw;
    }
  }
  __syncthreads();
  int lane = t & 63, w = t >> 6;
  int m31 = lane & 31;
  int khalf = (lane >> 5) * 8;
  f32x16 acc[4] = {};
#pragma unroll
  for (int ks = 0; ks < 8; ks++) {
    bf16x8 a = *(bf16x8*)&At[(w * 32 + m31) * LDS_STRIDE + ks * 16 + khalf];
#pragma unroll
    for (int nt = 0; nt < 4; nt++) {
      bf16x8 b = *(bf16x8*)&Bt[(nt * 32 + m31) * LDS_STRIDE + ks * 16 + khalf];
      acc[nt] = __builtin_amdgcn_mfma_f32_32x32x16_bf16(a, b, acc[nt], 0, 0, 0);
    }
  }
  __syncthreads();
  int rsel = (lane >> 5) * 4;
#pragma unroll
  for (int nt = 0; nt < 4; nt++) {
    int col = nt * 32 + m31;
    float bv = bias[col];
#pragma unroll
    for (int r = 0; r < 16; r++) {
      int rl = w * 32 + (r & 3) + 8 * (r >> 2) + rsel;
      float x = fmaxf(acc[nt][r] + bv, 0.f);
      At[rl * LDS_STRIDE + col] = (unsigned short)bf16rne(dsh[rl] * x);
    }
  }
  {
    const uint4* gw3 = (const uint4*)W3t;
#pragma unroll
    for (int i = 0; i < 4; i++) {
      int idx = i * 256 + t;
      int r = idx >> 4, c = idx & 15;
      *(uint4*)&Bt[r * LDS_STRIDE + c * 8] = gw3[idx];
    }
  }
  __syncthreads();
  f32x16 acc2[2] = {};
#pragma unroll
  for (int ks = 0; ks < 8; ks++) {
    bf16x8 a = *(bf16x8*)&At[(w * 32 + m31) * LDS_STRIDE + ks * 16 + khalf];
#pragma unroll
    for (int nt = 0; nt < 2; nt++) {
      bf16x8 b = *(bf16x8*)&Bt[(nt * 32 + m31) * LDS_STRIDE + ks * 16 + khalf];
      acc2[nt] = __builtin_amdgcn_mfma_f32_32x32x16_bf16(a, b, acc2[nt], 0, 0, 0);
    }
  }
  __syncthreads();  // At dead again; reuse as fp32 [128][40] staging
  float* Gst = (float*)At;
#pragma unroll
  for (int nt = 0; nt < 2; nt++) {
    int col = nt * 32 + m31;
    if (col < 40) {
#pragma unroll
      for (int r = 0; r < 16; r++) {
        int rl = w * 32 + (r & 3) + 8 * (r >> 2) + rsel;
        Gst[rl * 40 + col] = acc2[nt][r];
      }
    }
  }
  __syncthreads();
  {
    int lim = NN - rowBase;
    int lim4 = (lim >= 128) ? 1280 : lim * 10;
#pragma unroll
    for (int i = 0; i < 5; i++) {
      int idx = i * 256 + t;
      if (idx < lim4) {
        float4 vv = *(const float4*)&Gst[idx * 4];
        *(float4*)&G3[(size_t)rowBase * 40 + idx * 4] = vv;
      }
    }
  }
}

// ---------------------------------------------------------------------------
// fused 40-wide aggregation + bias + log_softmax over padded CSR
// ---------------------------------------------------------------------------
__global__ __launch_bounds__(256) void agg40_softmax(
    const float* __restrict__ G, const float* __restrict__ dis,
    const int* __restrict__ row_off, const unsigned short* __restrict__ csr,
    const float* __restrict__ b3, float* __restrict__ outp) {
  int node = __builtin_amdgcn_readfirstlane(blockIdx.x * 4 + (threadIdx.x >> 6));
  int lane = threadIdx.x & 63;
  int cl = lane < 40 ? lane : 39;
  float di = dis[node];
  float a = G[(size_t)node * 40 + cl];
  int beg = row_off[node], end = row_off[node + 1];
  if (beg < end) {
    uint4 cs = *(const uint4*)&csr[beg];
    for (int e = beg; e < end; e += 8) {
      int s0 = cs.x & 0xffff, s1 = cs.x >> 16;
      int s2 = cs.y & 0xffff, s3 = cs.y >> 16;
      int s4 = cs.z & 0xffff, s5 = cs.z >> 16;
      int s6 = cs.w & 0xffff, s7 = cs.w >> 16;
      float g0 = G[(size_t)s0 * 40 + cl];
      float g1 = G[(size_t)s1 * 40 + cl];
      float g2 = G[(size_t)s2 * 40 + cl];
      float g3 = G[(size_t)s3 * 40 + cl];
      float g4 = G[(size_t)s4 * 40 + cl];
      float g5 = G[(size_t)s5 * 40 + cl];
      float g6 = G[(size_t)s6 * 40 + cl];
      float g7 = G[(size_t)s7 * 40 + cl];
      if (e + 8 < end) cs = *(const uint4*)&csr[e + 8];
      a += g0 + g1 + g2 + g3 + g4 + g5 + g6 + g7;
    }
  }
  float o = di * a + b3[cl];
  float m = (lane < 40) ? o : -1e30f;
  for (int off = 32; off; off >>= 1) m = fmaxf(m, __shfl_xor(m, off, 64));
  float ex = (lane < 40) ? expf(o - m) : 0.f;
  float ssum = ex;
  for (int off = 32; off; off >>= 1) ssum += __shfl_xor(ssum, off, 64);
  float res = o - m - logf(ssum);
  if (lane < 40) outp[(size_t)node * 40 + lane] = res;
}

// ---------------------------------------------------------------------------
extern "C" void kernel_launch(void* const* d_in, const int* in_sizes, int n_in,
                              void* d_out, int out_size, void* d_ws,
                              size_t ws_size, hipStream_t stream) {
  const float* X = (const float*)d_in[0];
  const int* ei = (const int*)d_in[1];
  const float* W1 = (const float*)d_in[2];
  const float* b1 = (const float*)d_in[3];
  const float* W2 = (const float*)d_in[4];
  const float* b2 = (const float*)d_in[5];
  const float* W3 = (const float*)d_in[6];
  const float* b3 = (const float*)d_in[7];
  float* out = (float*)d_out;

  const int* src = ei;
  const int* dst = ei + EE;

  char* w = (char*)d_ws;
  auto carve = [&](size_t bytes) {
    char* p = w;
    w += (bytes + 255) & ~(size_t)255;
    return p;
  };
  int* cnt = (int*)carve(NN * 4);
  float* dis = (float*)carve(NN * 4);
  int* row_off = (int*)carve((NN + 1) * 4);
  int* cursor = (int*)carve(NN * 4);
  unsigned short* csr = (unsigned short*)carve((size_t)CSR_MAX * 2);
  unsigned short* Wt1 = (unsigned short*)carve(128 * 128 * 2);
  unsigned short* Wt2 = (unsigned short*)carve(128 * 128 * 2);
  unsigned short* W3t = (unsigned short*)carve(64 * 128 * 2);
  unsigned* Ab = (unsigned*)carve((size_t)MPAD * 128 * 2);       // 10.26 MB
  char* blk = carve(((size_t)NN + 1) * 128 * 4);                 // 20.5 MB
  unsigned* Xb = (unsigned*)blk;                                 // T(X), +row NN
  unsigned* H1b = (unsigned*)(blk + ((size_t)NN + 1) * 128 * 2); // T(h1), +row NN
  float* G3 = (float*)blk;  // layer-3 pre-agg [NN+1][40]; Xb dead by then

  hipMemsetAsync(cnt, 0, NN * 4, stream);
  hipMemsetAsync((char*)d_out + (size_t)NN * 40 * 4, 0, 4, stream);

  const int WB = NN / 4;      // 10000
  const int GB = MPAD / 128;  // 313

  // 1: edge atomics + weight transposes + dummy-row zeroing
  edge_w_kernel<<<786, 256, 0, stream>>>((const int4*)dst, cnt, W1, W2, W3,
                                         Wt1, Wt2, W3t, Xb, H1b);
  // 2: padded scan
  scan_kernel<<<1, 1024, 0, stream>>>((const int4*)cnt, row_off, cursor, dis);
  // 3: CSR fill + pad + X conversion
  fill_x_kernel<<<E4B + NB + 2500, 256, 0, stream>>>(
      (const int4*)src, (const int4*)dst, cursor, row_off, cnt, csr,
      (const float4*)X, dis, (uint2*)Xb);
  // 4: layer-1 aggregation + reg_loss
  agg1_reg<<<WB + 2500, 256, 0, stream>>>(Xb, dis, row_off, csr, Ab, src, dst,
                                          out + (size_t)NN * 40);
  // 5: layer-1 GEMM -> T(h1)
  gemm_mfma<<<GB, 256, 0, stream>>>(Ab, (const unsigned*)Wt1, b1, dis,
                                    (unsigned short*)H1b);
  // 6: layer-2 aggregation
  agg128b<<<WB, 256, 0, stream>>>(H1b, dis, row_off, csr, Ab);
  // 7: fused layer-2+3 GEMM -> G3
  gemm_mfma2<<<GB, 256, 0, stream>>>(Ab, (const unsigned*)Wt2, b2, dis, W3t,
                                     G3);
  // 8: layer-3 aggregation + bias + log_softmax -> out
  agg40_softmax<<<WB, 256, 0, stream>>>(G3, dis, row_off, csr, b3, out);
}